// Round 8
// baseline (4242.180 us; speedup 1.0000x reference)
//
#include <hip/hip_runtime.h>
#include <hip/hip_bf16.h>
#include <hip/hip_fp16.h>
#include <cstdio>
#include <cstdint>

typedef __hip_bfloat16 bf16;
using bf16x8 = __attribute__((ext_vector_type(8))) __bf16;
using f32x4  = __attribute__((ext_vector_type(4))) float;

#define LNUM 12
#define HDIM 768
#define NHEAD 12
#define DHEAD 64
#define FFDIM 3072
#define VOCAB 21128
#define VPAD  21248
#define NBATCH 64
#define SEQ 120
#define TITLEN 20
#define MROWS (NBATCH*SEQ)     // 7680
#define NTCLS (VPAD/128)       // 166

__device__ __forceinline__ float us2f(unsigned short u) {
  union { unsigned int u; float f; } c; c.u = ((unsigned int)u) << 16; return c.f;
}
__device__ __forceinline__ unsigned short f2us(float x) {
  bf16 h = __float2bfloat16(x);
  return *reinterpret_cast<unsigned short*>(&h);
}

// ---------------------------------------------------------------------------
// Layer GEMM: 128x128 tile, BK=32, 4 waves; ring-R LDS + counted vmcnt.
// R=3 (48KB, 3 blk/CU) for big grids (TLP hides latency); R=5 (80KB, 2 blk/CU)
// for small grids (pipeline depth hides latency: vmcnt(12) ~= 3 K-steps).
// EPI: 0 = store bf16; 1 = exact GELU + store; 2 = residual RMW (C=resid).
// ---------------------------------------------------------------------------
template<int EPI, int R, int MINB>
__launch_bounds__(256, MINB)
__global__ void gemm_bt(const bf16* __restrict__ A, const bf16* __restrict__ Bt,
                        const float* __restrict__ bias, bf16* __restrict__ C,
                        int N, int K, int nbx, int nby) {
  __shared__ __align__(16) unsigned short smA[R][128*32];
  __shared__ __align__(16) unsigned short smB[R][128*32];

  const int nwg = nbx * nby;
  const int orig = blockIdx.x;
  const int q8 = nwg >> 3, r8 = nwg & 7;
  const int xcd = orig & 7, lin = orig >> 3;
  const int pid = (xcd < r8 ? xcd * (q8 + 1) : r8 * (q8 + 1) + (xcd - r8) * q8) + lin;
  const int pg = 8 * nbx;
  const int g = pid / pg;
  const int rem0 = pid - g * pg;
  const int rows = min(8, nby - g * 8);
  const int by = g * 8 + rem0 % rows;
  const int bx = rem0 / rows;

  const int t = threadIdx.x;
  const int l = t & 63, w = t >> 6;
  const int wr = w >> 1, wc = w & 1;
  const int brow = by * 128;
  const int bcol = bx * 128;

  f32x4 acc[4][4];
#pragma unroll
  for (int i = 0; i < 4; ++i)
#pragma unroll
    for (int j = 0; j < 4; ++j) acc[i][j] = (f32x4){0.f, 0.f, 0.f, 0.f};

  const int srow = t >> 2;
  const int scol = ((t & 3) ^ ((t >> 3) & 3)) * 8;
  const bf16* gA0 = A  + (size_t)(brow + srow) * K + scol;
  const bf16* gA1 = gA0 + (size_t)64 * K;
  const bf16* gB0 = Bt + (size_t)(bcol + srow) * K + scol;
  const bf16* gB1 = gB0 + (size_t)64 * K;

  const int arow = l & 15;
  const int aslot = (l >> 4) ^ ((arow >> 1) & 3);
  const int aoff = (wr*64 + arow)*32 + aslot*8;
  const int boff = (wc*64 + arow)*32 + aslot*8;

  auto stage = [&](int buf, int k0) {
    __builtin_amdgcn_global_load_lds((const __attribute__((address_space(1))) void*)(gA0 + k0),
                                     (__attribute__((address_space(3))) void*)(smA[buf] + w*512), 16, 0, 0);
    __builtin_amdgcn_global_load_lds((const __attribute__((address_space(1))) void*)(gA1 + k0),
                                     (__attribute__((address_space(3))) void*)(smA[buf] + 2048 + w*512), 16, 0, 0);
    __builtin_amdgcn_global_load_lds((const __attribute__((address_space(1))) void*)(gB0 + k0),
                                     (__attribute__((address_space(3))) void*)(smB[buf] + w*512), 16, 0, 0);
    __builtin_amdgcn_global_load_lds((const __attribute__((address_space(1))) void*)(gB1 + k0),
                                     (__attribute__((address_space(3))) void*)(smB[buf] + 2048 + w*512), 16, 0, 0);
  };

  const int nk = K >> 5;                 // >= 24 for all shapes
#pragma unroll
  for (int i = 0; i < R - 1; ++i) if (i < nk) stage(i, i << 5);

  int buf = 0;
  for (int kt = 0; kt < nk; ++kt) {
    int rem = nk - 1 - kt; if (rem > R - 2) rem = R - 2;
    switch (rem) {          // wait until own tile-kt loads landed; keep rest in flight
      case 0: asm volatile("s_waitcnt vmcnt(0)"  ::: "memory"); break;
      case 1: asm volatile("s_waitcnt vmcnt(4)"  ::: "memory"); break;
      case 2: asm volatile("s_waitcnt vmcnt(8)"  ::: "memory"); break;
      default: asm volatile("s_waitcnt vmcnt(12)" ::: "memory"); break;
    }
    __builtin_amdgcn_s_barrier();        // tile kt visible; ring slot (kt+R-1)%R consumed
    if (kt + R - 1 < nk) {
      int nb = buf + (R - 1); if (nb >= R) nb -= R;
      stage(nb, (kt + R - 1) << 5);
    }
    __builtin_amdgcn_sched_barrier(0);

    const unsigned short* sa = smA[buf] + aoff;
    const unsigned short* sb = smB[buf] + boff;
    bf16x8 af[4], bg[4];
#pragma unroll
    for (int i = 0; i < 4; ++i) {
      af[i] = *reinterpret_cast<const bf16x8*>(sa + i*512);
      bg[i] = *reinterpret_cast<const bf16x8*>(sb + i*512);
    }
    __builtin_amdgcn_s_setprio(1);
#pragma unroll
    for (int i = 0; i < 4; ++i)
#pragma unroll
      for (int j = 0; j < 4; ++j)
        acc[i][j] = __builtin_amdgcn_mfma_f32_16x16x32_bf16(af[i], bg[j], acc[i][j], 0, 0, 0);
    __builtin_amdgcn_s_setprio(0);
    __builtin_amdgcn_sched_barrier(0);
    ++buf; if (buf >= R) buf -= R;
  }

#pragma unroll
  for (int i = 0; i < 4; ++i) {
    const int row = brow + wr*64 + i*16 + (l >> 4)*4;
#pragma unroll
    for (int j = 0; j < 4; ++j) {
      const int col = bcol + wc*64 + j*16 + (l & 15);
      const float bv = bias[col];
#pragma unroll
      for (int r = 0; r < 4; ++r) {
        const size_t idx = (size_t)(row + r) * N + col;
        float v = acc[i][j][r] + bv;
        if (EPI == 1) v = 0.5f * v * (1.0f + erff(v * 0.70710678118f));
        if (EPI == 2) v += __bfloat162float(C[idx]);   // residual RMW
        C[idx] = __float2bfloat16(v);
      }
    }
  }
}

// ---------------------------------------------------------------------------
// Classifier GEMM: 256x256 tile, 8 waves, BK=32, ring-4, 3-deep prefetch,
// 2 phases/tile. Epilogue: per-row-128 (max, sumexp) partials.
// ---------------------------------------------------------------------------
__launch_bounds__(512, 2)
__global__ void gemm_cls8(const bf16* __restrict__ A, const bf16* __restrict__ Bt,
                          const float* __restrict__ bias, float2* __restrict__ parts,
                          int K, int nbx, int nby) {
  __shared__ __align__(16) unsigned short lds[4][2][2][4096];  // ring, A/B, half

  const int nwg = nbx * nby;
  const int orig = blockIdx.x;
  const int q8 = nwg >> 3, r8 = nwg & 7;
  const int xcd = orig & 7, lin = orig >> 3;
  const int pid = (xcd < r8 ? xcd * (q8 + 1) : r8 * (q8 + 1) + (xcd - r8) * q8) + lin;
  const int pg = 8 * nbx;
  const int g = pid / pg;
  const int rem = pid - g * pg;
  const int rows = min(8, nby - g * 8);
  const int by = g * 8 + rem % rows;
  const int bx = rem / rows;

  const int t = threadIdx.x;            // 0..511
  const int l = t & 63, w = t >> 6;
  const int wm = w >> 2, wn = w & 3;    // 2 x 4 wave grid
  const int brow = by * 256;
  const int bcol = bx * 256;

  f32x4 acc[8][4];
#pragma unroll
  for (int m = 0; m < 8; ++m)
#pragma unroll
    for (int n = 0; n < 4; ++n) acc[m][n] = (f32x4){0.f, 0.f, 0.f, 0.f};

  const int srow = t >> 2;                        // 0..127
  const int scol = ((t & 3) ^ ((t >> 3) & 3)) * 8;
  const bf16* gA0 = A  + (size_t)(brow + srow) * K + scol;
  const bf16* gA1 = A  + (size_t)(brow + 128 + srow) * K + scol;
  const bf16* gB0 = Bt + (size_t)(bcol + srow) * K + scol;
  const bf16* gB1 = Bt + (size_t)(bcol + 128 + srow) * K + scol;

  const int arow = l & 15;
  const int aslot = (l >> 4) ^ ((arow >> 1) & 3);
  const int afrag = arow*32 + aslot*8;                       // + m*512
  const int bfrag = ((wn & 1)*64 + arow)*32 + aslot*8;       // + n*512

  auto stageA = [&](int rb, int k0) {
    __builtin_amdgcn_global_load_lds((const __attribute__((address_space(1))) void*)(gA0 + k0),
        (__attribute__((address_space(3))) void*)(&lds[rb][0][0][0] + w*512), 16, 0, 0);
    __builtin_amdgcn_global_load_lds((const __attribute__((address_space(1))) void*)(gA1 + k0),
        (__attribute__((address_space(3))) void*)(&lds[rb][0][1][0] + w*512), 16, 0, 0);
  };
  auto stageB = [&](int rb, int k0) {
    __builtin_amdgcn_global_load_lds((const __attribute__((address_space(1))) void*)(gB0 + k0),
        (__attribute__((address_space(3))) void*)(&lds[rb][1][0][0] + w*512), 16, 0, 0);
    __builtin_amdgcn_global_load_lds((const __attribute__((address_space(1))) void*)(gB1 + k0),
        (__attribute__((address_space(3))) void*)(&lds[rb][1][1][0] + w*512), 16, 0, 0);
  };

  const int nk = K >> 5;     // 24
  stageA(0, 0);   stageB(0, 0);
  stageA(1, 32);  stageB(1, 32);
  stageA(2, 64);  stageB(2, 64);

  for (int T = 0; T < nk; ++T) {
    const int rb = T & 3;
    if (T + 2 < nk)      asm volatile("s_waitcnt vmcnt(8)" ::: "memory");
    else if (T + 1 < nk) asm volatile("s_waitcnt vmcnt(4)" ::: "memory");
    else                 asm volatile("s_waitcnt vmcnt(0)" ::: "memory");
    __builtin_amdgcn_s_barrier();

    const unsigned short* sa = &lds[rb][0][wm][0] + afrag;
    const unsigned short* sb = &lds[rb][1][wn >> 1][0] + bfrag;

    bf16x8 af[8], bg[4];
#pragma unroll
    for (int m = 0; m < 4; ++m) af[m] = *reinterpret_cast<const bf16x8*>(sa + m*512);
#pragma unroll
    for (int n = 0; n < 4; ++n) bg[n] = *reinterpret_cast<const bf16x8*>(sb + n*512);
    if (T + 3 < nk) stageA((T + 3) & 3, (T + 3) << 5);
    asm volatile("s_waitcnt lgkmcnt(0)" ::: "memory");
    __builtin_amdgcn_sched_barrier(0);
    __builtin_amdgcn_s_setprio(1);
#pragma unroll
    for (int m = 0; m < 4; ++m)
#pragma unroll
      for (int n = 0; n < 4; ++n)
        acc[m][n] = __builtin_amdgcn_mfma_f32_16x16x32_bf16(af[m], bg[n], acc[m][n], 0, 0, 0);
    __builtin_amdgcn_s_setprio(0);
    __builtin_amdgcn_s_barrier();

#pragma unroll
    for (int m = 4; m < 8; ++m) af[m] = *reinterpret_cast<const bf16x8*>(sa + m*512);
    if (T + 3 < nk) stageB((T + 3) & 3, (T + 3) << 5);
    asm volatile("s_waitcnt lgkmcnt(0)" ::: "memory");
    __builtin_amdgcn_sched_barrier(0);
    __builtin_amdgcn_s_setprio(1);
#pragma unroll
    for (int m = 4; m < 8; ++m)
#pragma unroll
      for (int n = 0; n < 4; ++n)
        acc[m][n] = __builtin_amdgcn_mfma_f32_16x16x32_bf16(af[m], bg[n], acc[m][n], 0, 0, 0);
    __builtin_amdgcn_s_setprio(0);
  }

  __syncthreads();
  float* redm = reinterpret_cast<float*>(lds);       // [256][4]
  float* reds = redm + 1024;                         // [256][4]
  float b4[4];
#pragma unroll
  for (int n = 0; n < 4; ++n) b4[n] = bias[bcol + wn*64 + n*16 + (l & 15)];
  float vmax[8][4];
#pragma unroll
  for (int m = 0; m < 8; ++m)
#pragma unroll
    for (int r = 0; r < 4; ++r) {
      float mx = -3.0e38f;
#pragma unroll
      for (int n = 0; n < 4; ++n) mx = fmaxf(mx, acc[m][n][r] + b4[n]);
#pragma unroll
      for (int s = 1; s < 16; s <<= 1) mx = fmaxf(mx, __shfl_xor(mx, s));
      vmax[m][r] = mx;
    }
  if ((l & 15) == 0)
#pragma unroll
    for (int m = 0; m < 8; ++m)
#pragma unroll
      for (int r = 0; r < 4; ++r)
        redm[(wm*128 + m*16 + (l>>4)*4 + r)*4 + wn] = vmax[m][r];
  __syncthreads();
  const int pr = wn >> 1;
  float gmax[8][4], vsum[8][4];
#pragma unroll
  for (int m = 0; m < 8; ++m)
#pragma unroll
    for (int r = 0; r < 4; ++r) {
      const int rl = m*16 + (l>>4)*4 + r;
      const float gm = fmaxf(redm[(wm*128 + rl)*4 + pr*2], redm[(wm*128 + rl)*4 + pr*2 + 1]);
      gmax[m][r] = gm;
      float ss = 0.f;
#pragma unroll
      for (int n = 0; n < 4; ++n) ss += __expf(acc[m][n][r] + b4[n] - gm);
#pragma unroll
      for (int s = 1; s < 16; s <<= 1) ss += __shfl_xor(ss, s);
      vsum[m][r] = ss;
    }
  if ((l & 15) == 0)
#pragma unroll
    for (int m = 0; m < 8; ++m)
#pragma unroll
      for (int r = 0; r < 4; ++r)
        reds[(wm*128 + m*16 + (l>>4)*4 + r)*4 + wn] = vsum[m][r];
  __syncthreads();
  if ((wn & 1) == 0 && (l & 15) == 0)
#pragma unroll
    for (int m = 0; m < 8; ++m)
#pragma unroll
      for (int r = 0; r < 4; ++r) {
        const int rl = m*16 + (l>>4)*4 + r;
        const int row = brow + wm*128 + rl;
        parts[(size_t)row * NTCLS + bx*2 + pr] =
            make_float2(gmax[m][r], reds[(wm*128 + rl)*4 + wn] + reds[(wm*128 + rl)*4 + wn + 1]);
      }
}

// ---------------------------------------------------------------------------
// Fused attention: one block (4 waves) per (batch, head); key-segment split.
// ---------------------------------------------------------------------------
__launch_bounds__(256)
__global__ void attn_kernel(const bf16* __restrict__ qkv, bf16* __restrict__ ctx) {
  const int bh = blockIdx.x;
  const int b = bh / NHEAD, h = bh % NHEAD;
  __shared__ __align__(16) unsigned char smem[32768];
  __half2* hK = reinterpret_cast<__half2*>(smem);            // [SEQ][32]
  __half2* hV = reinterpret_cast<__half2*>(smem + 15360);    // [SEQ][32]
  __shared__ float pm[128], ps[128];
  const int t = threadIdx.x;

  for (int e = t; e < SEQ*DHEAD/8; e += 256) {
    const int s = e >> 3, d = (e & 7) * 8;
    const bf16* base = qkv + (size_t)(b*SEQ + s)*2304 + h*DHEAD + d;
    bf16x8 kk = *reinterpret_cast<const bf16x8*>(base + HDIM);
    bf16x8 vv = *reinterpret_cast<const bf16x8*>(base + 2*HDIM);
    __half2 ko[4], vo[4];
#pragma unroll
    for (int c = 0; c < 4; ++c) {
      ko[c] = __floats2half2_rn((float)kk[2*c], (float)kk[2*c+1]);
      vo[c] = __floats2half2_rn((float)vv[2*c], (float)vv[2*c+1]);
    }
    *reinterpret_cast<float4*>(&hK[s*32 + (d>>1)]) = *reinterpret_cast<const float4*>(ko);
    *reinterpret_cast<float4*>(&hV[s*32 + (d>>1)]) = *reinterpret_cast<const float4*>(vo);
  }

  const int w = t >> 6, l = t & 63;
  const int qg = w & 1, ks = w >> 1;
  const int i = qg*64 + l;
  __half2 q2[32];
  if (i < SEQ) {
    const bf16* qrow = qkv + (size_t)(b*SEQ + i)*2304 + h*DHEAD;
#pragma unroll
    for (int c = 0; c < 8; ++c) {
      bf16x8 qq = *reinterpret_cast<const bf16x8*>(qrow + c*8);
#pragma unroll
      for (int e = 0; e < 4; ++e)
        q2[c*4+e] = __floats2half2_rn((float)qq[2*e]*0.125f, (float)qq[2*e+1]*0.125f);
    }
  } else {
#pragma unroll
    for (int c = 0; c < 32; ++c) q2[c] = __floats2half2_rn(0.f, 0.f);
  }
  __syncthreads();

  const int jmax = (i < TITLEN) ? TITLEN : (i + 1);
  const int j0 = ks ? 60 : 0;
  const int j1 = ks ? SEQ : 60;
  float m = -1e30f, sum = 0.f;
  float4 acc[16];
#pragma unroll
  for (int c = 0; c < 16; ++c) acc[c] = make_float4(0.f, 0.f, 0.f, 0.f);

  for (int j = j0; j < j1; ++j) {
    const float4* kr = reinterpret_cast<const float4*>(&hK[j*32]);
    __half2 s2 = __floats2half2_rn(0.f, 0.f);
#pragma unroll
    for (int c = 0; c < 8; ++c) {
      float4 kk4 = kr[c];
      const __half2* kp = reinterpret_cast<const __half2*>(&kk4);
      s2 = __hfma2(q2[4*c+0], kp[0], s2);
      s2 = __hfma2(q2[4*c+1], kp[1], s2);
      s2 = __hfma2(q2[4*c+2], kp[2], s2);
      s2 = __hfma2(q2[4*c+3], kp[3], s2);
    }
    float s = __low2float(s2) + __high2float(s2);
    s = (j < jmax && i < SEQ) ? s : -1e30f;
    if (__any(s > m + 8.f)) {
      const float mn = fmaxf(m, s);
      const float al = __expf(m - mn);
      sum *= al;
#pragma unroll
      for (int c = 0; c < 16; ++c) {
        acc[c].x *= al; acc[c].y *= al; acc[c].z *= al; acc[c].w *= al;
      }
      m = mn;
    }
    const float p = __expf(s - m);
    sum += p;
    const float4* vr = reinterpret_cast<const float4*>(&hV[j*32]);
#pragma unroll
    for (int c = 0; c < 8; ++c) {
      float4 vv4 = vr[c];
      const __half2* vp = reinterpret_cast<const __half2*>(&vv4);
#pragma unroll
      for (int e = 0; e < 2; ++e) {
        const float2 lo = __half22float2(vp[2*e]);
        const float2 hi = __half22float2(vp[2*e+1]);
        float4& a = acc[c*2+e];
        a.x += p*lo.x; a.y += p*lo.y; a.z += p*hi.x; a.w += p*hi.y;
      }
    }
  }

  __syncthreads();
  __half2* ex = reinterpret_cast<__half2*>(smem);
  if (ks == 1) {
    pm[qg*64 + l] = m;
    ps[qg*64 + l] = sum;
#pragma unroll
    for (int c = 0; c < 16; ++c) {
      ex[(qg*64 + l)*32 + 2*c]     = __floats2half2_rn(acc[c].x, acc[c].y);
      ex[(qg*64 + l)*32 + 2*c + 1] = __floats2half2_rn(acc[c].z, acc[c].w);
    }
  }
  __syncthreads();
  if (ks == 0 && i < SEQ) {
    const float m1 = pm[qg*64 + l], s1 = ps[qg*64 + l];
    const float M  = fmaxf(m, m1);
    const float a0 = __expf(m - M);
    const float a1 = __expf(m1 - M);
    const float inv = 1.0f / (sum * a0 + s1 * a1);
    bf16* orow = ctx + (size_t)(b*SEQ + i)*HDIM + h*DHEAD;
#pragma unroll
    for (int c = 0; c < 8; ++c) {
      const float4 x0 = acc[c*2], x1 = acc[c*2+1];
      const float2 e0 = __half22float2(ex[(qg*64 + l)*32 + 4*c + 0]);
      const float2 e1 = __half22float2(ex[(qg*64 + l)*32 + 4*c + 1]);
      const float2 e2 = __half22float2(ex[(qg*64 + l)*32 + 4*c + 2]);
      const float2 e3 = __half22float2(ex[(qg*64 + l)*32 + 4*c + 3]);
      bf16x8 o;
      o[0] = (__bf16)((x0.x*a0 + e0.x*a1) * inv);
      o[1] = (__bf16)((x0.y*a0 + e0.y*a1) * inv);
      o[2] = (__bf16)((x0.z*a0 + e1.x*a1) * inv);
      o[3] = (__bf16)((x0.w*a0 + e1.y*a1) * inv);
      o[4] = (__bf16)((x1.x*a0 + e2.x*a1) * inv);
      o[5] = (__bf16)((x1.y*a0 + e2.y*a1) * inv);
      o[6] = (__bf16)((x1.z*a0 + e3.x*a1) * inv);
      o[7] = (__bf16)((x1.w*a0 + e3.y*a1) * inv);
      *reinterpret_cast<bf16x8*>(orow + c*8) = o;
    }
  }
}

// ---------------------------------------------------------------------------
// LN kernels (one wave per row). embed_ln2 builds the residual stream;
// ln_only reads resid (already updated by GEMM residual-RMW) -> writes hb.
// ---------------------------------------------------------------------------
__launch_bounds__(64)
__global__ void embed_ln2(const int* __restrict__ x, const float* __restrict__ wemb,
                          const float* __restrict__ pemb, const float* __restrict__ temb,
                          const float* __restrict__ lw, const float* __restrict__ lb,
                          bf16* __restrict__ resid, bf16* __restrict__ hb) {
  const int row = blockIdx.x;
  const int s = row % SEQ;
  const int tok = x[row];
  const int l = threadIdx.x;
  const int c0 = l * 12;
  float v[12]; float sum = 0.f, sq = 0.f;
#pragma unroll
  for (int i = 0; i < 3; ++i) {
    const float4 a = *reinterpret_cast<const float4*>(wemb + (size_t)tok*HDIM + c0 + i*4);
    const float4 b = *reinterpret_cast<const float4*>(pemb + s*HDIM + c0 + i*4);
    const float4 c = *reinterpret_cast<const float4*>(temb + c0 + i*4);
    v[i*4+0] = a.x + b.x + c.x; v[i*4+1] = a.y + b.y + c.y;
    v[i*4+2] = a.z + b.z + c.z; v[i*4+3] = a.w + b.w + c.w;
#pragma unroll
    for (int e = 0; e < 4; ++e) { sum += v[i*4+e]; sq += v[i*4+e]*v[i*4+e]; }
  }
#pragma unroll
  for (int m = 1; m < 64; m <<= 1) { sum += __shfl_xor(sum, m); sq += __shfl_xor(sq, m); }
  const float mean = sum * (1.0f/HDIM);
  const float rs = rsqrtf(sq*(1.0f/HDIM) - mean*mean + 1e-12f);
  unsigned short* rp = (unsigned short*)resid + (size_t)row*HDIM + c0;
  unsigned short* hp = (unsigned short*)hb    + (size_t)row*HDIM + c0;
#pragma unroll
  for (int i = 0; i < 3; ++i) {
    ushort4 o;
    o.x = f2us((v[i*4+0]-mean)*rs*lw[c0+i*4+0] + lb[c0+i*4+0]);
    o.y = f2us((v[i*4+1]-mean)*rs*lw[c0+i*4+1] + lb[c0+i*4+1]);
    o.z = f2us((v[i*4+2]-mean)*rs*lw[c0+i*4+2] + lb[c0+i*4+2]);
    o.w = f2us((v[i*4+3]-mean)*rs*lw[c0+i*4+3] + lb[c0+i*4+3]);
    *reinterpret_cast<ushort4*>(hp + i*4) = o;
    ushort4 ro;
    ro.x = f2us(v[i*4+0]); ro.y = f2us(v[i*4+1]);
    ro.z = f2us(v[i*4+2]); ro.w = f2us(v[i*4+3]);
    *reinterpret_cast<ushort4*>(rp + i*4) = ro;
  }
}

__launch_bounds__(64)
__global__ void ln_only(const bf16* __restrict__ resid, bf16* __restrict__ hb,
                        const float* __restrict__ lw, const float* __restrict__ lb) {
  const int row = blockIdx.x;
  const int l = threadIdx.x;
  const int c0 = l * 12;
  const unsigned short* rp = (const unsigned short*)resid + (size_t)row*HDIM + c0;
  float v[12]; float sum = 0.f, sq = 0.f;
#pragma unroll
  for (int i = 0; i < 3; ++i) {
    const ushort4 ra = *reinterpret_cast<const ushort4*>(rp + i*4);
    v[i*4+0] = us2f(ra.x); v[i*4+1] = us2f(ra.y);
    v[i*4+2] = us2f(ra.z); v[i*4+3] = us2f(ra.w);
#pragma unroll
    for (int e = 0; e < 4; ++e) { sum += v[i*4+e]; sq += v[i*4+e]*v[i*4+e]; }
  }
#pragma unroll
  for (int m = 1; m < 64; m <<= 1) { sum += __shfl_xor(sum, m); sq += __shfl_xor(sq, m); }
  const float mean = sum * (1.0f/HDIM);
  const float rs = rsqrtf(sq*(1.0f/HDIM) - mean*mean + 1e-12f);
  unsigned short* hp = (unsigned short*)hb + (size_t)row*HDIM + c0;
#pragma unroll
  for (int i = 0; i < 3; ++i) {
    ushort4 o;
    o.x = f2us((v[i*4+0]-mean)*rs*lw[c0+i*4+0] + lb[c0+i*4+0]);
    o.y = f2us((v[i*4+1]-mean)*rs*lw[c0+i*4+1] + lb[c0+i*4+1]);
    o.z = f2us((v[i*4+2]-mean)*rs*lw[c0+i*4+2] + lb[c0+i*4+2]);
    o.w = f2us((v[i*4+3]-mean)*rs*lw[c0+i*4+3] + lb[c0+i*4+3]);
    *reinterpret_cast<ushort4*>(hp + i*4) = o;
  }
}

// ---------------------------------------------------------------------------
// Weight transpose+convert (all 12 layers in one dispatch + per-layer fallback)
// ---------------------------------------------------------------------------
__device__ __forceinline__ void transpose_block(const float* in, bf16* out,
                                                int K, int N, int bx, int by) {
  __shared__ float tile[32][33];
  const int tx = threadIdx.x, ty = threadIdx.y;   // (32,8)
#pragma unroll
  for (int r = 0; r < 32; r += 8)
    tile[ty+r][tx] = in[(size_t)(by + ty + r) * N + bx + tx];
  __syncthreads();
#pragma unroll
  for (int r = 0; r < 32; r += 8)
    out[(size_t)(bx + ty + r) * K + by + tx] = __float2bfloat16(tile[tx][ty+r]);
}

__device__ __forceinline__ void transpose_sel(int id, int lay,
    const float* qw, const float* kw, const float* vw, const float* aow,
    const float* f1w, const float* f2w,
    bf16* wqkvT, bf16* waoT, bf16* wf1T, bf16* wf2T,
    size_t wstride_qkv, size_t wstride_ao, size_t wstride_f) {
  const size_t o768 = (size_t)768*768, of1 = (size_t)768*FFDIM;
  const float* in; bf16* out; int K, N, nbx;
  if (id < 2304) {
    const int z = id / 576; id -= z * 576;
    in = ((z == 0) ? qw : (z == 1) ? kw : (z == 2) ? vw : aow) + (size_t)lay*o768;
    out = (z < 3) ? (wqkvT + (size_t)lay*wstride_qkv + (size_t)z*o768)
                  : (waoT + (size_t)lay*wstride_ao);
    K = 768; N = 768; nbx = 24;
  } else if (id < 4608) {
    id -= 2304; in = f1w + (size_t)lay*of1; out = wf1T + (size_t)lay*wstride_f;
    K = 768; N = 3072; nbx = 96;
  } else {
    id -= 4608; in = f2w + (size_t)lay*of1; out = wf2T + (size_t)lay*wstride_f;
    K = 3072; N = 768; nbx = 24;
  }
  transpose_block(in, out, K, N, (id % nbx) * 32, (id / nbx) * 32);
}

__global__ void transpose_all(const float* qw, const float* kw, const float* vw,
                              const float* aow, const float* f1w, const float* f2w,
                              bf16* wqkvT, bf16* waoT, bf16* wf1T, bf16* wf2T) {
  transpose_sel(blockIdx.x % 6912, blockIdx.x / 6912, qw, kw, vw, aow, f1w, f2w,
                wqkvT, waoT, wf1T, wf2T,
                (size_t)2304*768, (size_t)768*768, (size_t)768*FFDIM);
}

__global__ void transpose_layer(const float* qw, const float* kw, const float* vw,
                                const float* aow, const float* f1w, const float* f2w,
                                bf16* wqkvT, bf16* waoT, bf16* wf1T, bf16* wf2T,
                                int lay) {
  transpose_sel(blockIdx.x, 0, qw + (size_t)lay*768*768, kw + (size_t)lay*768*768,
                vw + (size_t)lay*768*768, aow + (size_t)lay*768*768,
                f1w + (size_t)lay*768*FFDIM, f2w + (size_t)lay*768*FFDIM,
                wqkvT, waoT, wf1T, wf2T, 0, 0, 0);
}

__global__ void transpose_cls(const float* __restrict__ in, bf16* __restrict__ out) {
  __shared__ float tile[32][33];
  const int bx = blockIdx.x*32, by = blockIdx.y*32;
  const int tx = threadIdx.x, ty = threadIdx.y;   // (32,8)
#pragma unroll
  for (int r = 0; r < 32; r += 8) {
    const int n = bx + tx;
    tile[ty+r][tx] = (n < VOCAB) ? in[(size_t)(by + ty + r) * VOCAB + n] : 0.f;
  }
  __syncthreads();
#pragma unroll
  for (int r = 0; r < 32; r += 8) {
    const int n = bx + ty + r;
    if (n < VPAD) out[(size_t)n * 768 + by + tx] = __float2bfloat16(tile[tx][ty+r]);
  }
}

__global__ void prep_bias(const float* __restrict__ qb, const float* __restrict__ kb,
                          const float* __restrict__ vb, const float* __restrict__ clsb,
                          float* __restrict__ qkvb, float* __restrict__ clsbp) {
  const int i = blockIdx.x*256 + threadIdx.x;
  if (i < LNUM*2304) {
    const int l = i / 2304, n = i % 2304;
    float v;
    if (n < 768) v = qb[l*768 + n];
    else if (n < 1536) v = kb[l*768 + n - 768];
    else v = vb[l*768 + n - 1536];
    qkvb[i] = v;
  }
  if (i < VPAD) clsbp[i] = (i < VOCAB) ? clsb[i] : -1e9f;
}

__launch_bounds__(64)
__global__ void ce_merge(const float2* __restrict__ parts, const bf16* __restrict__ hb,
                         const bf16* __restrict__ wclsT, const float* __restrict__ clsb,
                         const int* __restrict__ y, float* __restrict__ out) {
  const int row = blockIdx.x;
  const int l = threadIdx.x;
  const int tgt = y[row];
  float tl = 0.f;
  for (int i = l; i < HDIM; i += 64)
    tl += __bfloat162float(hb[(size_t)row*HDIM + i]) * __bfloat162float(wclsT[(size_t)tgt*HDIM + i]);
#pragma unroll
  for (int m = 1; m < 64; m <<= 1) tl += __shfl_xor(tl, m);
  float mx = -3.0e38f;
  for (int i = l; i < NTCLS; i += 64) mx = fmaxf(mx, parts[(size_t)row*NTCLS + i].x);
#pragma unroll
  for (int m = 1; m < 64; m <<= 1) mx = fmaxf(mx, __shfl_xor(mx, m));
  float ss = 0.f;
  for (int i = l; i < NTCLS; i += 64) {
    const float2 p = parts[(size_t)row*NTCLS + i];
    ss += p.y * __expf(p.x - mx);
  }
#pragma unroll
  for (int m = 1; m < 64; m <<= 1) ss += __shfl_xor(ss, m);
  if (l == 0) {
    const float lse = mx + logf(ss);
    atomicAdd(out, (lse - (tl + clsb[tgt])) * (1.0f / MROWS));
  }
}

// ---------------------------------------------------------------------------
extern "C" void kernel_launch(void* const* d_in, const int* in_sizes, int n_in,
                              void* d_out, int out_size, void* d_ws, size_t ws_size,
                              hipStream_t stream) {
  const int*   x     = (const int*)d_in[0];
  const int*   y     = (const int*)d_in[1];
  const float* wemb  = (const float*)d_in[2];
  const float* pemb  = (const float*)d_in[3];
  const float* temb  = (const float*)d_in[4];
  const float* elnw  = (const float*)d_in[5];
  const float* elnb  = (const float*)d_in[6];
  const float* qw    = (const float*)d_in[7];
  const float* qb    = (const float*)d_in[8];
  const float* kw    = (const float*)d_in[9];
  const float* kb    = (const float*)d_in[10];
  const float* vw    = (const float*)d_in[11];
  const float* vb    = (const float*)d_in[12];
  const float* aow   = (const float*)d_in[13];
  const float* aob   = (const float*)d_in[14];
  const float* alnw  = (const float*)d_in[15];
  const float* alnb  = (const float*)d_in[16];
  const float* f1w   = (const float*)d_in[17];
  const float* f1b   = (const float*)d_in[18];
  const float* f2w   = (const float*)d_in[19];
  const float* f2b   = (const float*)d_in[20];
  const float* flnw  = (const float*)d_in[21];
  const float* flnb  = (const float*)d_in[22];
  const float* clsw  = (const float*)d_in[23];
  const float* clsb  = (const float*)d_in[24];

  char* p = (char*)d_ws;
  auto alloc = [&](size_t bytes) { char* r = p; p += (bytes + 255) & ~(size_t)255; return r; };
  bf16*  wclsT = (bf16*)alloc((size_t)VPAD*768*2);
  float* qkvb  = (float*)alloc((size_t)LNUM*2304*4);
  float* clsbp = (float*)alloc((size_t)VPAD*4);
  bf16*  resid = (bf16*)alloc((size_t)MROWS*HDIM*2);
  bf16*  hb    = (bf16*)alloc((size_t)MROWS*HDIM*2);
  bf16*  qkv   = (bf16*)alloc((size_t)MROWS*2304*2);
  bf16*  ctxb  = (bf16*)alloc((size_t)MROWS*HDIM*2);
  bf16*  ffh   = (bf16*)alloc((size_t)MROWS*FFDIM*2);
  float2* parts = (float2*)alloc((size_t)MROWS*NTCLS*sizeof(float2));

  const size_t sz_qkvT = (size_t)2304*768*2;
  const size_t sz_aoT  = (size_t)768*768*2;
  const size_t sz_fT   = (size_t)768*FFDIM*2;
  const size_t per_layer_w = ((sz_qkvT+255)&~255ULL) + ((sz_aoT+255)&~255ULL)
                           + 2*((sz_fT+255)&~255ULL);
  const size_t fixed = (size_t)(p - (char*)d_ws);
  const bool big = (fixed + (size_t)LNUM * per_layer_w) <= ws_size;
  const int nlw = big ? LNUM : 1;
  bf16* wqkvT = (bf16*)alloc((size_t)nlw * sz_qkvT);
  bf16* waoT  = (bf16*)alloc((size_t)nlw * sz_aoT);
  bf16* wf1T  = (bf16*)alloc((size_t)nlw * sz_fT);
  bf16* wf2T  = (bf16*)alloc((size_t)nlw * sz_fT);
  if ((size_t)(p - (char*)d_ws) > ws_size) {
    fprintf(stderr, "kernel_launch: ws too small (%zu > %zu)\n",
            (size_t)(p - (char*)d_ws), ws_size);
    return;
  }

  hipMemsetAsync(d_out, 0, (size_t)out_size * sizeof(float), stream);
  prep_bias<<<108, 256, 0, stream>>>(qb, kb, vb, clsb, qkvb, clsbp);
  transpose_cls<<<dim3(VPAD/32, 768/32), dim3(32,8), 0, stream>>>(clsw, wclsT);
  if (big)
    transpose_all<<<LNUM*6912, dim3(32,8), 0, stream>>>(qw, kw, vw, aow, f1w, f2w,
                                                        wqkvT, waoT, wf1T, wf2T);
  embed_ln2<<<MROWS, 64, 0, stream>>>(x, wemb, pemb, temb, elnw, elnb, resid, hb);

  for (int l = 0; l < LNUM; ++l) {
    bf16* lqkvT; bf16* laoT; bf16* lf1T; bf16* lf2T;
    if (big) {
      lqkvT = wqkvT + (size_t)l*2304*768;
      laoT  = waoT  + (size_t)l*768*768;
      lf1T  = wf1T  + (size_t)l*768*FFDIM;
      lf2T  = wf2T  + (size_t)l*768*FFDIM;
    } else {
      lqkvT = wqkvT; laoT = waoT; lf1T = wf1T; lf2T = wf2T;
      transpose_layer<<<6912, dim3(32,8), 0, stream>>>(qw, kw, vw, aow, f1w, f2w,
                                                       lqkvT, laoT, lf1T, lf2T, l);
    }

    gemm_bt<0,3,3><<<18*60, 256, 0, stream>>>(hb, lqkvT, qkvb + l*2304, qkv,
                                              2304, HDIM, 18, 60);
    attn_kernel<<<NBATCH*NHEAD, 256, 0, stream>>>(qkv, ctxb);
    gemm_bt<2,5,2><<<6*60, 256, 0, stream>>>(ctxb, laoT, aob + l*HDIM, resid,
                                             768, HDIM, 6, 60);
    ln_only<<<MROWS, 64, 0, stream>>>(resid, hb, alnw + l*HDIM, alnb + l*HDIM);
    gemm_bt<1,3,3><<<24*60, 256, 0, stream>>>(hb, lf1T, f1b + l*FFDIM, ffh,
                                              FFDIM, HDIM, 24, 60);
    gemm_bt<2,5,2><<<6*60, 256, 0, stream>>>(ffh, lf2T, f2b + l*HDIM, resid,
                                             768, FFDIM, 6, 60);
    ln_only<<<MROWS, 64, 0, stream>>>(resid, hb, flnw + l*HDIM, flnb + l*HDIM);
  }

  gemm_cls8<<<83*30, 512, 0, stream>>>(hb, wclsT, clsbp, parts, HDIM, 83, 30);
  ce_merge<<<MROWS, 64, 0, stream>>>(parts, hb, wclsT, clsb, y, (float*)d_out);
}

// Round 9
// 3451.908 us; speedup vs baseline: 1.2289x; 1.2289x over previous
//
#include <hip/hip_runtime.h>
#include <hip/hip_bf16.h>
#include <hip/hip_fp16.h>
#include <cstdio>
#include <cstdint>

typedef __hip_bfloat16 bf16;
using bf16x8 = __attribute__((ext_vector_type(8))) __bf16;
using f32x4  = __attribute__((ext_vector_type(4))) float;

#define LNUM 12
#define HDIM 768
#define NHEAD 12
#define DHEAD 64
#define FFDIM 3072
#define VOCAB 21128
#define VPAD  21248
#define NBATCH 64
#define SEQ 120
#define TITLEN 20
#define MROWS (NBATCH*SEQ)     // 7680
#define NTCLS (VPAD/128)       // 166

__device__ __forceinline__ float us2f(unsigned short u) {
  union { unsigned int u; float f; } c; c.u = ((unsigned int)u) << 16; return c.f;
}
__device__ __forceinline__ unsigned short f2us(float x) {
  bf16 h = __float2bfloat16(x);
  return *reinterpret_cast<unsigned short*>(&h);
}

// ---------------------------------------------------------------------------
// Layer GEMM (round-7 verified config): 128x128 tile, BK=32, 4 waves,
// ring-3 LDS + counted vmcnt, T2 swizzle both-sides, XCD-chunked grid.
// EPI: 0 = store bf16, 1 = exact GELU + store bf16
// ---------------------------------------------------------------------------
template<int EPI>
__launch_bounds__(256, 3)
__global__ void gemm_bt(const bf16* __restrict__ A, const bf16* __restrict__ Bt,
                        const float* __restrict__ bias, bf16* __restrict__ C,
                        int N, int K, int nbx, int nby) {
  __shared__ __align__(16) unsigned short smA[3][128*32];
  __shared__ __align__(16) unsigned short smB[3][128*32];

  const int nwg = nbx * nby;
  const int orig = blockIdx.x;
  const int q8 = nwg >> 3, r8 = nwg & 7;
  const int xcd = orig & 7, lin = orig >> 3;
  const int pid = (xcd < r8 ? xcd * (q8 + 1) : r8 * (q8 + 1) + (xcd - r8) * q8) + lin;
  const int pg = 8 * nbx;
  const int g = pid / pg;
  const int rem = pid - g * pg;
  const int rows = min(8, nby - g * 8);
  const int by = g * 8 + rem % rows;
  const int bx = rem / rows;

  const int t = threadIdx.x;
  const int l = t & 63, w = t >> 6;
  const int wr = w >> 1, wc = w & 1;
  const int brow = by * 128;
  const int bcol = bx * 128;

  f32x4 acc[4][4];
#pragma unroll
  for (int i = 0; i < 4; ++i)
#pragma unroll
    for (int j = 0; j < 4; ++j) acc[i][j] = (f32x4){0.f, 0.f, 0.f, 0.f};

  const int srow = t >> 2;
  const int scol = ((t & 3) ^ ((t >> 3) & 3)) * 8;
  const bf16* gA0 = A  + (size_t)(brow + srow) * K + scol;
  const bf16* gA1 = gA0 + (size_t)64 * K;
  const bf16* gB0 = Bt + (size_t)(bcol + srow) * K + scol;
  const bf16* gB1 = gB0 + (size_t)64 * K;

  const int arow = l & 15;
  const int aslot = (l >> 4) ^ ((arow >> 1) & 3);
  const int aoff = (wr*64 + arow)*32 + aslot*8;
  const int boff = (wc*64 + arow)*32 + aslot*8;

  auto stage = [&](int buf, int k0) {
    __builtin_amdgcn_global_load_lds((const __attribute__((address_space(1))) void*)(gA0 + k0),
                                     (__attribute__((address_space(3))) void*)(smA[buf] + w*512), 16, 0, 0);
    __builtin_amdgcn_global_load_lds((const __attribute__((address_space(1))) void*)(gA1 + k0),
                                     (__attribute__((address_space(3))) void*)(smA[buf] + 2048 + w*512), 16, 0, 0);
    __builtin_amdgcn_global_load_lds((const __attribute__((address_space(1))) void*)(gB0 + k0),
                                     (__attribute__((address_space(3))) void*)(smB[buf] + w*512), 16, 0, 0);
    __builtin_amdgcn_global_load_lds((const __attribute__((address_space(1))) void*)(gB1 + k0),
                                     (__attribute__((address_space(3))) void*)(smB[buf] + 2048 + w*512), 16, 0, 0);
  };

  const int nk = K >> 5;
  stage(0, 0);
  stage(1, 32);

  int buf = 0;
  for (int kt = 0; kt < nk; ++kt) {
    if (kt + 1 < nk) asm volatile("s_waitcnt vmcnt(4)" ::: "memory");
    else             asm volatile("s_waitcnt vmcnt(0)" ::: "memory");
    __builtin_amdgcn_s_barrier();
    if (kt + 2 < nk) {
      int nb = buf + 2; if (nb >= 3) nb -= 3;
      stage(nb, (kt + 2) << 5);
    }
    __builtin_amdgcn_sched_barrier(0);

    const unsigned short* sa = smA[buf] + aoff;
    const unsigned short* sb = smB[buf] + boff;
    bf16x8 af[4], bg[4];
#pragma unroll
    for (int i = 0; i < 4; ++i) {
      af[i] = *reinterpret_cast<const bf16x8*>(sa + i*512);
      bg[i] = *reinterpret_cast<const bf16x8*>(sb + i*512);
    }
    __builtin_amdgcn_s_setprio(1);
#pragma unroll
    for (int i = 0; i < 4; ++i)
#pragma unroll
      for (int j = 0; j < 4; ++j)
        acc[i][j] = __builtin_amdgcn_mfma_f32_16x16x32_bf16(af[i], bg[j], acc[i][j], 0, 0, 0);
    __builtin_amdgcn_s_setprio(0);
    __builtin_amdgcn_sched_barrier(0);
    ++buf; if (buf >= 3) buf -= 3;
  }

#pragma unroll
  for (int i = 0; i < 4; ++i) {
    const int row = brow + wr*64 + i*16 + (l >> 4)*4;
#pragma unroll
    for (int j = 0; j < 4; ++j) {
      const int col = bcol + wc*64 + j*16 + (l & 15);
      const float bv = bias[col];
#pragma unroll
      for (int r = 0; r < 4; ++r) {
        float v = acc[i][j][r] + bv;
        if (EPI == 1) v = 0.5f * v * (1.0f + erff(v * 0.70710678118f));
        C[(size_t)(row + r) * N + col] = __float2bfloat16(v);
      }
    }
  }
}

// ---------------------------------------------------------------------------
// Classifier GEMM: 256x256 tile, 8 waves, BK=32, ring-4, 3-deep prefetch,
// 2 phases/tile. Epilogue: per-row-128 (max, sumexp) partials.
// ---------------------------------------------------------------------------
__launch_bounds__(512, 2)
__global__ void gemm_cls8(const bf16* __restrict__ A, const bf16* __restrict__ Bt,
                          const float* __restrict__ bias, float2* __restrict__ parts,
                          int K, int nbx, int nby) {
  __shared__ __align__(16) unsigned short lds[4][2][2][4096];  // ring, A/B, half

  const int nwg = nbx * nby;
  const int orig = blockIdx.x;
  const int q8 = nwg >> 3, r8 = nwg & 7;
  const int xcd = orig & 7, lin = orig >> 3;
  const int pid = (xcd < r8 ? xcd * (q8 + 1) : r8 * (q8 + 1) + (xcd - r8) * q8) + lin;
  const int pg = 8 * nbx;
  const int g = pid / pg;
  const int rem = pid - g * pg;
  const int rows = min(8, nby - g * 8);
  const int by = g * 8 + rem % rows;
  const int bx = rem / rows;

  const int t = threadIdx.x;            // 0..511
  const int l = t & 63, w = t >> 6;
  const int wm = w >> 2, wn = w & 3;    // 2 x 4 wave grid
  const int brow = by * 256;
  const int bcol = bx * 256;

  f32x4 acc[8][4];
#pragma unroll
  for (int m = 0; m < 8; ++m)
#pragma unroll
    for (int n = 0; n < 4; ++n) acc[m][n] = (f32x4){0.f, 0.f, 0.f, 0.f};

  const int srow = t >> 2;                        // 0..127
  const int scol = ((t & 3) ^ ((t >> 3) & 3)) * 8;
  const bf16* gA0 = A  + (size_t)(brow + srow) * K + scol;
  const bf16* gA1 = A  + (size_t)(brow + 128 + srow) * K + scol;
  const bf16* gB0 = Bt + (size_t)(bcol + srow) * K + scol;
  const bf16* gB1 = Bt + (size_t)(bcol + 128 + srow) * K + scol;

  const int arow = l & 15;
  const int aslot = (l >> 4) ^ ((arow >> 1) & 3);
  const int afrag = arow*32 + aslot*8;                       // + m*512
  const int bfrag = ((wn & 1)*64 + arow)*32 + aslot*8;       // + n*512

  auto stageA = [&](int rb, int k0) {
    __builtin_amdgcn_global_load_lds((const __attribute__((address_space(1))) void*)(gA0 + k0),
        (__attribute__((address_space(3))) void*)(&lds[rb][0][0][0] + w*512), 16, 0, 0);
    __builtin_amdgcn_global_load_lds((const __attribute__((address_space(1))) void*)(gA1 + k0),
        (__attribute__((address_space(3))) void*)(&lds[rb][0][1][0] + w*512), 16, 0, 0);
  };
  auto stageB = [&](int rb, int k0) {
    __builtin_amdgcn_global_load_lds((const __attribute__((address_space(1))) void*)(gB0 + k0),
        (__attribute__((address_space(3))) void*)(&lds[rb][1][0][0] + w*512), 16, 0, 0);
    __builtin_amdgcn_global_load_lds((const __attribute__((address_space(1))) void*)(gB1 + k0),
        (__attribute__((address_space(3))) void*)(&lds[rb][1][1][0] + w*512), 16, 0, 0);
  };

  const int nk = K >> 5;     // 24
  stageA(0, 0);   stageB(0, 0);
  stageA(1, 32);  stageB(1, 32);
  stageA(2, 64);  stageB(2, 64);

  for (int T = 0; T < nk; ++T) {
    const int rb = T & 3;
    if (T + 2 < nk)      asm volatile("s_waitcnt vmcnt(8)" ::: "memory");
    else if (T + 1 < nk) asm volatile("s_waitcnt vmcnt(4)" ::: "memory");
    else                 asm volatile("s_waitcnt vmcnt(0)" ::: "memory");
    __builtin_amdgcn_s_barrier();

    const unsigned short* sa = &lds[rb][0][wm][0] + afrag;
    const unsigned short* sb = &lds[rb][1][wn >> 1][0] + bfrag;

    bf16x8 af[8], bg[4];
#pragma unroll
    for (int m = 0; m < 4; ++m) af[m] = *reinterpret_cast<const bf16x8*>(sa + m*512);
#pragma unroll
    for (int n = 0; n < 4; ++n) bg[n] = *reinterpret_cast<const bf16x8*>(sb + n*512);
    if (T + 3 < nk) stageA((T + 3) & 3, (T + 3) << 5);
    asm volatile("s_waitcnt lgkmcnt(0)" ::: "memory");
    __builtin_amdgcn_sched_barrier(0);
    __builtin_amdgcn_s_setprio(1);
#pragma unroll
    for (int m = 0; m < 4; ++m)
#pragma unroll
      for (int n = 0; n < 4; ++n)
        acc[m][n] = __builtin_amdgcn_mfma_f32_16x16x32_bf16(af[m], bg[n], acc[m][n], 0, 0, 0);
    __builtin_amdgcn_s_setprio(0);
    __builtin_amdgcn_s_barrier();

#pragma unroll
    for (int m = 4; m < 8; ++m) af[m] = *reinterpret_cast<const bf16x8*>(sa + m*512);
    if (T + 3 < nk) stageB((T + 3) & 3, (T + 3) << 5);
    asm volatile("s_waitcnt lgkmcnt(0)" ::: "memory");
    __builtin_amdgcn_sched_barrier(0);
    __builtin_amdgcn_s_setprio(1);
#pragma unroll
    for (int m = 4; m < 8; ++m)
#pragma unroll
      for (int n = 0; n < 4; ++n)
        acc[m][n] = __builtin_amdgcn_mfma_f32_16x16x32_bf16(af[m], bg[n], acc[m][n], 0, 0, 0);
    __builtin_amdgcn_s_setprio(0);
  }

  __syncthreads();
  float* redm = reinterpret_cast<float*>(lds);       // [256][4]
  float* reds = redm + 1024;                         // [256][4]
  float b4[4];
#pragma unroll
  for (int n = 0; n < 4; ++n) b4[n] = bias[bcol + wn*64 + n*16 + (l & 15)];
  float vmax[8][4];
#pragma unroll
  for (int m = 0; m < 8; ++m)
#pragma unroll
    for (int r = 0; r < 4; ++r) {
      float mx = -3.0e38f;
#pragma unroll
      for (int n = 0; n < 4; ++n) mx = fmaxf(mx, acc[m][n][r] + b4[n]);
#pragma unroll
      for (int s = 1; s < 16; s <<= 1) mx = fmaxf(mx, __shfl_xor(mx, s));
      vmax[m][r] = mx;
    }
  if ((l & 15) == 0)
#pragma unroll
    for (int m = 0; m < 8; ++m)
#pragma unroll
      for (int r = 0; r < 4; ++r)
        redm[(wm*128 + m*16 + (l>>4)*4 + r)*4 + wn] = vmax[m][r];
  __syncthreads();
  const int pr = wn >> 1;
  float gmax[8][4], vsum[8][4];
#pragma unroll
  for (int m = 0; m < 8; ++m)
#pragma unroll
    for (int r = 0; r < 4; ++r) {
      const int rl = m*16 + (l>>4)*4 + r;
      const float gm = fmaxf(redm[(wm*128 + rl)*4 + pr*2], redm[(wm*128 + rl)*4 + pr*2 + 1]);
      gmax[m][r] = gm;
      float ss = 0.f;
#pragma unroll
      for (int n = 0; n < 4; ++n) ss += __expf(acc[m][n][r] + b4[n] - gm);
#pragma unroll
      for (int s = 1; s < 16; s <<= 1) ss += __shfl_xor(ss, s);
      vsum[m][r] = ss;
    }
  if ((l & 15) == 0)
#pragma unroll
    for (int m = 0; m < 8; ++m)
#pragma unroll
      for (int r = 0; r < 4; ++r)
        reds[(wm*128 + m*16 + (l>>4)*4 + r)*4 + wn] = vsum[m][r];
  __syncthreads();
  if ((wn & 1) == 0 && (l & 15) == 0)
#pragma unroll
    for (int m = 0; m < 8; ++m)
#pragma unroll
      for (int r = 0; r < 4; ++r) {
        const int rl = m*16 + (l>>4)*4 + r;
        const int row = brow + wm*128 + rl;
        parts[(size_t)row * NTCLS + bx*2 + pr] =
            make_float2(gmax[m][r], reds[(wm*128 + rl)*4 + wn] + reds[(wm*128 + rl)*4 + wn + 1]);
      }
}

// ---------------------------------------------------------------------------
// MFMA attention: one block (4 waves) per (batch, head). Wave w owns queries
// [w*32, w*32+32). LDS: Qs[128][64], Ks[128][64], Vt[64][128], P strips
// [32][128]/wave — all bf16, all XOR-swizzled (slot ^= row&7, 16B slots).
// QK^T and PV use the verified gemm_bt fragment pattern (A-row/Bt-row,
// 8-contig-k; C: col=l&15, row=(l>>4)*4+r). Softmax: 16-lane shfl reduce.
// ---------------------------------------------------------------------------
__launch_bounds__(256, 2)
__global__ void attn_mfma(const bf16* __restrict__ qkv, bf16* __restrict__ ctx) {
  const int bh = blockIdx.x;
  const int b = bh / NHEAD, h = bh % NHEAD;
  __shared__ __align__(16) unsigned char smem[81920];
  unsigned short* Qs = reinterpret_cast<unsigned short*>(smem);           // [128][64]
  unsigned short* Ks = reinterpret_cast<unsigned short*>(smem + 16384);   // [128][64]
  unsigned short* Vt = reinterpret_cast<unsigned short*>(smem + 32768);   // [64][128]

  const int t = threadIdx.x;
  const int l = t & 63, w = t >> 6;

  // ---- zero Vt (pad cols must be exact 0: 0*NaN hazard) + Q/K pad rows ----
  const float4 z4 = make_float4(0.f, 0.f, 0.f, 0.f);
#pragma unroll
  for (int rd = 0; rd < 4; ++rd)
    *reinterpret_cast<float4*>(smem + 32768 + (rd*256 + t)*16) = z4;
  if (t < 128) {
    const int mtx = t >> 6;            // 0 = Qs, 1 = Ks
    const int sl = t & 63;             // rows 120..127 x 8 slots
    *reinterpret_cast<float4*>(smem + mtx*16384 + (960 + sl)*16) = z4;
  }
  __syncthreads();

  // ---- stage Q,K via global_load_lds (pre-swizzled source); Vt transposed ----
  const bf16* qbase = qkv + (size_t)(b*SEQ)*2304 + h*DHEAD;
#pragma unroll
  for (int rd = 0; rd < 4; ++rd) {
    const int idx = rd*256 + t;
    if (idx < 960) {
      const int row = idx >> 3, slot = idx & 7;
      const int srccol = (slot ^ (row & 7)) * 8;
      const bf16* src = qbase + (size_t)row*2304 + srccol;
      __builtin_amdgcn_global_load_lds((const __attribute__((address_space(1))) void*)(src),
          (__attribute__((address_space(3))) void*)(Qs + idx*8), 16, 0, 0);
      __builtin_amdgcn_global_load_lds((const __attribute__((address_space(1))) void*)(src + HDIM),
          (__attribute__((address_space(3))) void*)(Ks + idx*8), 16, 0, 0);
    }
  }
#pragma unroll
  for (int rd = 0; rd < 4; ++rd) {
    const int e = rd*256 + t;
    if (e < 960) {
      const int j = e >> 3, d8 = (e & 7) * 8;
      bf16x8 vv = *reinterpret_cast<const bf16x8*>(qbase + (size_t)j*2304 + 2*HDIM + d8);
      const int cs = j >> 3;
#pragma unroll
      for (int q = 0; q < 8; ++q) {
        const int d = d8 + q;
        Vt[d*128 + ((cs ^ (d & 7))*8) + (j & 7)] =
            reinterpret_cast<const unsigned short*>(&vv)[q];
      }
    }
  }
  __syncthreads();   // drains vmcnt + lgkmcnt

  // ---- QK^T: sacc[rt][ct] covers S[w*32+rt*16+..][ct*16+..] ----
  f32x4 sacc[2][8];
#pragma unroll
  for (int rt = 0; rt < 2; ++rt)
#pragma unroll
    for (int ct = 0; ct < 8; ++ct) sacc[rt][ct] = (f32x4){0.f, 0.f, 0.f, 0.f};

#pragma unroll
  for (int ks = 0; ks < 2; ++ks) {
    const int kslot = (l >> 4) + 4*ks;
    bf16x8 aq[2];
#pragma unroll
    for (int rt = 0; rt < 2; ++rt) {
      const int row = w*32 + rt*16 + (l & 15);
      aq[rt] = *reinterpret_cast<const bf16x8*>(Qs + row*64 + ((kslot ^ (row & 7))*8));
    }
#pragma unroll
    for (int ct = 0; ct < 8; ++ct) {
      const int rk = ct*16 + (l & 15);
      bf16x8 bk = *reinterpret_cast<const bf16x8*>(Ks + rk*64 + ((kslot ^ (rk & 7))*8));
#pragma unroll
      for (int rt = 0; rt < 2; ++rt)
        sacc[rt][ct] = __builtin_amdgcn_mfma_f32_16x16x32_bf16(aq[rt], bk, sacc[rt][ct], 0, 0, 0);
    }
  }

  // ---- mask + scale + softmax; write unnormalized P (bf16) to own strip ----
  unsigned short* Pw = reinterpret_cast<unsigned short*>(smem + 49152 + w*8192); // [32][128]
  float rinv[2][4];
#pragma unroll
  for (int rt = 0; rt < 2; ++rt) {
#pragma unroll
    for (int r = 0; r < 4; ++r) {
      const int i = w*32 + rt*16 + (l >> 4)*4 + r;
      float sv[8];
      float best = -3.0e38f;
#pragma unroll
      for (int ct = 0; ct < 8; ++ct) {
        const int j = ct*16 + (l & 15);
        const bool ok = (j < SEQ) && ((i < TITLEN) ? (j < TITLEN) : (j < TITLEN || j <= i));
        sv[ct] = ok ? sacc[rt][ct][r] * 0.125f : -1e30f;
        best = fmaxf(best, sv[ct]);
      }
#pragma unroll
      for (int m = 1; m < 16; m <<= 1) best = fmaxf(best, __shfl_xor(best, m));
      float ss = 0.f;
      const int rowl = rt*16 + (l >> 4)*4 + r;
#pragma unroll
      for (int ct = 0; ct < 8; ++ct) {
        const float p = __expf(sv[ct] - best);
        ss += p;
        const int col = ct*16 + (l & 15);
        const int cs = col >> 3;
        Pw[rowl*128 + ((cs ^ (rowl & 7))*8) + (col & 7)] = f2us(p);
      }
#pragma unroll
      for (int m = 1; m < 16; m <<= 1) ss += __shfl_xor(ss, m);
      rinv[rt][r] = 1.0f / ss;
    }
  }
  asm volatile("s_waitcnt lgkmcnt(0)" ::: "memory");   // own P writes complete
  __builtin_amdgcn_sched_barrier(0);                   // rule 18

  // ---- PV: oacc[rt][dt] = P(strip) @ Vt^T ----
  f32x4 oacc[2][4];
#pragma unroll
  for (int rt = 0; rt < 2; ++rt)
#pragma unroll
    for (int dt = 0; dt < 4; ++dt) oacc[rt][dt] = (f32x4){0.f, 0.f, 0.f, 0.f};

#pragma unroll
  for (int ks = 0; ks < 4; ++ks) {
    const int kslot = (l >> 4) + 4*ks;
    bf16x8 ap[2];
#pragma unroll
    for (int rt = 0; rt < 2; ++rt) {
      const int rowl = rt*16 + (l & 15);
      ap[rt] = *reinterpret_cast<const bf16x8*>(Pw + rowl*128 + ((kslot ^ (rowl & 7))*8));
    }
#pragma unroll
    for (int dt = 0; dt < 4; ++dt) {
      const int rv = dt*16 + (l & 15);
      bf16x8 bv = *reinterpret_cast<const bf16x8*>(Vt + rv*128 + ((kslot ^ (rv & 7))*8));
#pragma unroll
      for (int rt = 0; rt < 2; ++rt)
        oacc[rt][dt] = __builtin_amdgcn_mfma_f32_16x16x32_bf16(ap[rt], bv, oacc[rt][dt], 0, 0, 0);
    }
  }

  // ---- store ctx ----
  bf16* obase = ctx + (size_t)(b*SEQ)*HDIM + h*DHEAD;
#pragma unroll
  for (int rt = 0; rt < 2; ++rt)
#pragma unroll
    for (int r = 0; r < 4; ++r) {
      const int i = w*32 + rt*16 + (l >> 4)*4 + r;
      if (i < SEQ) {
#pragma unroll
        for (int dt = 0; dt < 4; ++dt) {
          const int d = dt*16 + (l & 15);
          obase[(size_t)i*HDIM + d] = __float2bfloat16(oacc[rt][dt][r] * rinv[rt][r]);
        }
      }
    }
}

// ---------------------------------------------------------------------------
// LN kernels (one wave per row), bf16 residual stream.
// ---------------------------------------------------------------------------
__launch_bounds__(64)
__global__ void embed_ln2(const int* __restrict__ x, const float* __restrict__ wemb,
                          const float* __restrict__ pemb, const float* __restrict__ temb,
                          const float* __restrict__ lw, const float* __restrict__ lb,
                          bf16* __restrict__ resid, bf16* __restrict__ hb) {
  const int row = blockIdx.x;
  const int s = row % SEQ;
  const int tok = x[row];
  const int l = threadIdx.x;
  const int c0 = l * 12;
  float v[12]; float sum = 0.f, sq = 0.f;
#pragma unroll
  for (int i = 0; i < 3; ++i) {
    const float4 a = *reinterpret_cast<const float4*>(wemb + (size_t)tok*HDIM + c0 + i*4);
    const float4 b = *reinterpret_cast<const float4*>(pemb + s*HDIM + c0 + i*4);
    const float4 c = *reinterpret_cast<const float4*>(temb + c0 + i*4);
    v[i*4+0] = a.x + b.x + c.x; v[i*4+1] = a.y + b.y + c.y;
    v[i*4+2] = a.z + b.z + c.z; v[i*4+3] = a.w + b.w + c.w;
#pragma unroll
    for (int e = 0; e < 4; ++e) { sum += v[i*4+e]; sq += v[i*4+e]*v[i*4+e]; }
  }
#pragma unroll
  for (int m = 1; m < 64; m <<= 1) { sum += __shfl_xor(sum, m); sq += __shfl_xor(sq, m); }
  const float mean = sum * (1.0f/HDIM);
  const float rs = rsqrtf(sq*(1.0f/HDIM) - mean*mean + 1e-12f);
  unsigned short* rp = (unsigned short*)resid + (size_t)row*HDIM + c0;
  unsigned short* hp = (unsigned short*)hb    + (size_t)row*HDIM + c0;
#pragma unroll
  for (int i = 0; i < 3; ++i) {
    ushort4 o;
    o.x = f2us((v[i*4+0]-mean)*rs*lw[c0+i*4+0] + lb[c0+i*4+0]);
    o.y = f2us((v[i*4+1]-mean)*rs*lw[c0+i*4+1] + lb[c0+i*4+1]);
    o.z = f2us((v[i*4+2]-mean)*rs*lw[c0+i*4+2] + lb[c0+i*4+2]);
    o.w = f2us((v[i*4+3]-mean)*rs*lw[c0+i*4+3] + lb[c0+i*4+3]);
    *reinterpret_cast<ushort4*>(hp + i*4) = o;
    ushort4 ro;
    ro.x = f2us(v[i*4+0]); ro.y = f2us(v[i*4+1]);
    ro.z = f2us(v[i*4+2]); ro.w = f2us(v[i*4+3]);
    *reinterpret_cast<ushort4*>(rp + i*4) = ro;
  }
}

__launch_bounds__(64)
__global__ void res_ln2(bf16* __restrict__ resid, bf16* __restrict__ hb,
                        const bf16* __restrict__ add,
                        const float* __restrict__ lw, const float* __restrict__ lb) {
  const int row = blockIdx.x;
  const int l = threadIdx.x;
  const int c0 = l * 12;
  const unsigned short* rp = (const unsigned short*)resid + (size_t)row*HDIM + c0;
  const unsigned short* ap = (const unsigned short*)add   + (size_t)row*HDIM + c0;
  float v[12]; float sum = 0.f, sq = 0.f;
#pragma unroll
  for (int i = 0; i < 3; ++i) {
    const ushort4 ra = *reinterpret_cast<const ushort4*>(rp + i*4);
    const ushort4 aa = *reinterpret_cast<const ushort4*>(ap + i*4);
    v[i*4+0] = us2f(ra.x) + us2f(aa.x);
    v[i*4+1] = us2f(ra.y) + us2f(aa.y);
    v[i*4+2] = us2f(ra.z) + us2f(aa.z);
    v[i*4+3] = us2f(ra.w) + us2f(aa.w);
#pragma unroll
    for (int e = 0; e < 4; ++e) { sum += v[i*4+e]; sq += v[i*4+e]*v[i*4+e]; }
  }
#pragma unroll
  for (int m = 1; m < 64; m <<= 1) { sum += __shfl_xor(sum, m); sq += __shfl_xor(sq, m); }
  const float mean = sum * (1.0f/HDIM);
  const float rs = rsqrtf(sq*(1.0f/HDIM) - mean*mean + 1e-12f);
  unsigned short* rw = (unsigned short*)resid + (size_t)row*HDIM + c0;
  unsigned short* hp = (unsigned short*)hb    + (size_t)row*HDIM + c0;
#pragma unroll
  for (int i = 0; i < 3; ++i) {
    ushort4 ro;
    ro.x = f2us(v[i*4+0]); ro.y = f2us(v[i*4+1]);
    ro.z = f2us(v[i*4+2]); ro.w = f2us(v[i*4+3]);
    *reinterpret_cast<ushort4*>(rw + i*4) = ro;
    ushort4 o;
    o.x = f2us((v[i*4+0]-mean)*rs*lw[c0+i*4+0] + lb[c0+i*4+0]);
    o.y = f2us((v[i*4+1]-mean)*rs*lw[c0+i*4+1] + lb[c0+i*4+1]);
    o.z = f2us((v[i*4+2]-mean)*rs*lw[c0+i*4+2] + lb[c0+i*4+2]);
    o.w = f2us((v[i*4+3]-mean)*rs*lw[c0+i*4+3] + lb[c0+i*4+3]);
    *reinterpret_cast<ushort4*>(hp + i*4) = o;
  }
}

// ---------------------------------------------------------------------------
// Weight transpose+convert (all 12 layers in one dispatch + per-layer fallback)
// ---------------------------------------------------------------------------
__device__ __forceinline__ void transpose_block(const float* in, bf16* out,
                                                int K, int N, int bx, int by) {
  __shared__ float tile[32][33];
  const int tx = threadIdx.x, ty = threadIdx.y;   // (32,8)
#pragma unroll
  for (int r = 0; r < 32; r += 8)
    tile[ty+r][tx] = in[(size_t)(by + ty + r) * N + bx + tx];
  __syncthreads();
#pragma unroll
  for (int r = 0; r < 32; r += 8)
    out[(size_t)(bx + ty + r) * K + by + tx] = __float2bfloat16(tile[tx][ty+r]);
}

__device__ __forceinline__ void transpose_sel(int id, int lay,
    const float* qw, const float* kw, const float* vw, const float* aow,
    const float* f1w, const float* f2w,
    bf16* wqkvT, bf16* waoT, bf16* wf1T, bf16* wf2T,
    size_t wstride_qkv, size_t wstride_ao, size_t wstride_f) {
  const size_t o768 = (size_t)768*768, of1 = (size_t)768*FFDIM;
  const float* in; bf16* out; int K, N, nbx;
  if (id < 2304) {
    const int z = id / 576; id -= z * 576;
    in = ((z == 0) ? qw : (z == 1) ? kw : (z == 2) ? vw : aow) + (size_t)lay*o768;
    out = (z < 3) ? (wqkvT + (size_t)lay*wstride_qkv + (size_t)z*o768)
                  : (waoT + (size_t)lay*wstride_ao);
    K = 768; N = 768; nbx = 24;
  } else if (id < 4608) {
    id -= 2304; in = f1w + (size_t)lay*of1; out = wf1T + (size_t)lay*wstride_f;
    K = 768; N = 3072; nbx = 96;
  } else {
    id -= 4608; in = f2w + (size_t)lay*of1; out = wf2T + (size_t)lay*wstride_f;
    K = 3072; N = 768; nbx = 24;
  }
  transpose_block(in, out, K, N, (id % nbx) * 32, (id / nbx) * 32);
}

__global__ void transpose_all(const float* qw, const float* kw, const float* vw,
                              const float* aow, const float* f1w, const float* f2w,
                              bf16* wqkvT, bf16* waoT, bf16* wf1T, bf16* wf2T) {
  transpose_sel(blockIdx.x % 6912, blockIdx.x / 6912, qw, kw, vw, aow, f1w, f2w,
                wqkvT, waoT, wf1T, wf2T,
                (size_t)2304*768, (size_t)768*768, (size_t)768*FFDIM);
}

__global__ void transpose_layer(const float* qw, const float* kw, const float* vw,
                                const float* aow, const float* f1w, const float* f2w,
                                bf16* wqkvT, bf16* waoT, bf16* wf1T, bf16* wf2T,
                                int lay) {
  transpose_sel(blockIdx.x, 0, qw + (size_t)lay*768*768, kw + (size_t)lay*768*768,
                vw + (size_t)lay*768*768, aow + (size_t)lay*768*768,
                f1w + (size_t)lay*768*FFDIM, f2w + (size_t)lay*768*FFDIM,
                wqkvT, waoT, wf1T, wf2T, 0, 0, 0);
}

__global__ void transpose_cls(const float* __restrict__ in, bf16* __restrict__ out) {
  __shared__ float tile[32][33];
  const int bx = blockIdx.x*32, by = blockIdx.y*32;
  const int tx = threadIdx.x, ty = threadIdx.y;   // (32,8)
#pragma unroll
  for (int r = 0; r < 32; r += 8) {
    const int n = bx + tx;
    tile[ty+r][tx] = (n < VOCAB) ? in[(size_t)(by + ty + r) * VOCAB + n] : 0.f;
  }
  __syncthreads();
#pragma unroll
  for (int r = 0; r < 32; r += 8) {
    const int n = bx + ty + r;
    if (n < VPAD) out[(size_t)n * 768 + by + tx] = __float2bfloat16(tile[tx][ty+r]);
  }
}

__global__ void prep_bias(const float* __restrict__ qb, const float* __restrict__ kb,
                          const float* __restrict__ vb, const float* __restrict__ clsb,
                          float* __restrict__ qkvb, float* __restrict__ clsbp) {
  const int i = blockIdx.x*256 + threadIdx.x;
  if (i < LNUM*2304) {
    const int l = i / 2304, n = i % 2304;
    float v;
    if (n < 768) v = qb[l*768 + n];
    else if (n < 1536) v = kb[l*768 + n - 768];
    else v = vb[l*768 + n - 1536];
    qkvb[i] = v;
  }
  if (i < VPAD) clsbp[i] = (i < VOCAB) ? clsb[i] : -1e9f;
}

__launch_bounds__(64)
__global__ void ce_merge(const float2* __restrict__ parts, const bf16* __restrict__ hb,
                         const bf16* __restrict__ wclsT, const float* __restrict__ clsb,
                         const int* __restrict__ y, float* __restrict__ out) {
  const int row = blockIdx.x;
  const int l = threadIdx.x;
  const int tgt = y[row];
  float tl = 0.f;
  for (int i = l; i < HDIM; i += 64)
    tl += __bfloat162float(hb[(size_t)row*HDIM + i]) * __bfloat162float(wclsT[(size_t)tgt*HDIM + i]);
#pragma unroll
  for (int m = 1; m < 64; m <<= 1) tl += __shfl_xor(tl, m);
  float mx = -3.0e38f;
  for (int i = l; i < NTCLS; i += 64) mx = fmaxf(mx, parts[(size_t)row*NTCLS + i].x);
#pragma unroll
  for (int m = 1; m < 64; m <<= 1) mx = fmaxf(mx, __shfl_xor(mx, m));
  float ss = 0.f;
  for (int i = l; i < NTCLS; i += 64) {
    const float2 p = parts[(size_t)row*NTCLS + i];
    ss += p.y * __expf(p.x - mx);
  }
#pragma unroll
  for (int m = 1; m < 64; m <<= 1) ss += __shfl_xor(ss, m);
  if (l == 0) {
    const float lse = mx + logf(ss);
    atomicAdd(out, (lse - (tl + clsb[tgt])) * (1.0f / MROWS));
  }
}

// ---------------------------------------------------------------------------
extern "C" void kernel_launch(void* const* d_in, const int* in_sizes, int n_in,
                              void* d_out, int out_size, void* d_ws, size_t ws_size,
                              hipStream_t stream) {
  const int*   x     = (const int*)d_in[0];
  const int*   y     = (const int*)d_in[1];
  const float* wemb  = (const float*)d_in[2];
  const float* pemb  = (const float*)d_in[3];
  const float* temb  = (const float*)d_in[4];
  const float* elnw  = (const float*)d_in[5];
  const float* elnb  = (const float*)d_in[6];
  const float* qw    = (const float*)d_in[7];
  const float* qb    = (const float*)d_in[8];
  const float* kw    = (const float*)d_in[9];
  const float* kb    = (const float*)d_in[10];
  const float* vw    = (const float*)d_in[11];
  const float* vb    = (const float*)d_in[12];
  const float* aow   = (const float*)d_in[13];
  const float* aob   = (const float*)d_in[14];
  const float* alnw  = (const float*)d_in[15];
  const float* alnb  = (const float*)d_in[16];
  const float* f1w   = (const float*)d_in[17];
  const float* f1b   = (const float*)d_in[18];
  const float* f2w   = (const float*)d_in[19];
  const float* f2b   = (const float*)d_in[20];
  const float* flnw  = (const float*)d_in[21];
  const float* flnb  = (const float*)d_in[22];
  const float* clsw  = (const float*)d_in[23];
  const float* clsb  = (const float*)d_in[24];

  char* p = (char*)d_ws;
  auto alloc = [&](size_t bytes) { char* r = p; p += (bytes + 255) & ~(size_t)255; return r; };
  bf16*  wclsT = (bf16*)alloc((size_t)VPAD*768*2);
  float* qkvb  = (float*)alloc((size_t)LNUM*2304*4);
  float* clsbp = (float*)alloc((size_t)VPAD*4);
  bf16*  resid = (bf16*)alloc((size_t)MROWS*HDIM*2);
  bf16*  hb    = (bf16*)alloc((size_t)MROWS*HDIM*2);
  bf16*  qkv   = (bf16*)alloc((size_t)MROWS*2304*2);
  bf16*  ctxb  = (bf16*)alloc((size_t)MROWS*HDIM*2);
  bf16*  tmp   = (bf16*)alloc((size_t)MROWS*HDIM*2);
  bf16*  ffh   = (bf16*)alloc((size_t)MROWS*FFDIM*2);
  float2* parts = (float2*)alloc((size_t)MROWS*NTCLS*sizeof(float2));

  const size_t sz_qkvT = (size_t)2304*768*2;
  const size_t sz_aoT  = (size_t)768*768*2;
  const size_t sz_fT   = (size_t)768*FFDIM*2;
  const size_t per_layer_w = ((sz_qkvT+255)&~255ULL) + ((sz_aoT+255)&~255ULL)
                           + 2*((sz_fT+255)&~255ULL);
  const size_t fixed = (size_t)(p - (char*)d_ws);
  const bool big = (fixed + (size_t)LNUM * per_layer_w) <= ws_size;
  const int nlw = big ? LNUM : 1;
  bf16* wqkvT = (bf16*)alloc((size_t)nlw * sz_qkvT);
  bf16* waoT  = (bf16*)alloc((size_t)nlw * sz_aoT);
  bf16* wf1T  = (bf16*)alloc((size_t)nlw * sz_fT);
  bf16* wf2T  = (bf16*)alloc((size_t)nlw * sz_fT);
  if ((size_t)(p - (char*)d_ws) > ws_size) {
    fprintf(stderr, "kernel_launch: ws too small (%zu > %zu)\n",
            (size_t)(p - (char*)d_ws), ws_size);
    return;
  }

  hipMemsetAsync(d_out, 0, (size_t)out_size * sizeof(float), stream);
  prep_bias<<<108, 256, 0, stream>>>(qb, kb, vb, clsb, qkvb, clsbp);
  transpose_cls<<<dim3(VPAD/32, 768/32), dim3(32,8), 0, stream>>>(clsw, wclsT);
  if (big)
    transpose_all<<<LNUM*6912, dim3(32,8), 0, stream>>>(qw, kw, vw, aow, f1w, f2w,
                                                        wqkvT, waoT, wf1T, wf2T);
  embed_ln2<<<MROWS, 64, 0, stream>>>(x, wemb, pemb, temb, elnw, elnb, resid, hb);

  for (int l = 0; l < LNUM; ++l) {
    bf16* lqkvT; bf16* laoT; bf16* lf1T; bf16* lf2T;
    if (big) {
      lqkvT = wqkvT + (size_t)l*2304*768;
      laoT  = waoT  + (size_t)l*768*768;
      lf1T  = wf1T  + (size_t)l*768*FFDIM;
      lf2T  = wf2T  + (size_t)l*768*FFDIM;
    } else {
      lqkvT = wqkvT; laoT = waoT; lf1T = wf1T; lf2T = wf2T;
      transpose_layer<<<6912, dim3(32,8), 0, stream>>>(qw, kw, vw, aow, f1w, f2w,
                                                       lqkvT, laoT, lf1T, lf2T, l);
    }

    gemm_bt<0><<<18*60, 256, 0, stream>>>(hb, lqkvT, qkvb + l*2304, qkv,
                                          2304, HDIM, 18, 60);
    attn_mfma<<<NBATCH*NHEAD, 256, 0, stream>>>(qkv, ctxb);
    gemm_bt<0><<<6*60, 256, 0, stream>>>(ctxb, laoT, aob + l*HDIM, tmp,
                                         768, HDIM, 6, 60);
    res_ln2<<<MROWS, 64, 0, stream>>>(resid, hb, tmp, alnw + l*HDIM, alnb + l*HDIM);
    gemm_bt<1><<<24*60, 256, 0, stream>>>(hb, lf1T, f1b + l*FFDIM, ffh,
                                          FFDIM, HDIM, 24, 60);
    gemm_bt<0><<<6*60, 256, 0, stream>>>(ffh, lf2T, f2b + l*HDIM, tmp,
                                         768, FFDIM, 6, 60);
    res_ln2<<<MROWS, 64, 0, stream>>>(resid, hb, tmp, flnw + l*HDIM, flnb + l*HDIM);
  }

  gemm_cls8<<<83*30, 512, 0, stream>>>(hb, wclsT, clsbp, parts, HDIM, 83, 30);
  ce_merge<<<MROWS, 64, 0, stream>>>(parts, hb, wclsT, clsb, y, (float*)d_out);
}

// Round 10
// 3163.046 us; speedup vs baseline: 1.3412x; 1.0913x over previous
//
#include <hip/hip_runtime.h>
#include <hip/hip_bf16.h>
#include <hip/hip_fp16.h>
#include <cstdio>
#include <cstdint>

typedef __hip_bfloat16 bf16;
using bf16x8 = __attribute__((ext_vector_type(8))) __bf16;
using f32x4  = __attribute__((ext_vector_type(4))) float;

#define LNUM 12
#define HDIM 768
#define NHEAD 12
#define DHEAD 64
#define FFDIM 3072
#define VOCAB 21128
#define VPAD  21248
#define NBATCH 64
#define SEQ 120
#define TITLEN 20
#define MROWS (NBATCH*SEQ)     // 7680
#define NTCLS (VPAD/128)       // 166

__device__ __forceinline__ float us2f(unsigned short u) {
  union { unsigned int u; float f; } c; c.u = ((unsigned int)u) << 16; return c.f;
}
__device__ __forceinline__ unsigned short f2us(float x) {
  bf16 h = __float2bfloat16(x);
  return *reinterpret_cast<unsigned short*>(&h);
}

// ---------------------------------------------------------------------------
// Layer GEMM v5: 128x128 tile, BK=32, 4 waves; ring-2 LDS (32 KB -> 4 blk/CU,
// 16 waves/CU TLP). Loop: vmcnt(4) -> bar -> ds_read -> lgkm0 -> bar ->
// stage(kt+2 into just-read slot) -> MFMA. Cross-block TLP hides the
// shallower prefetch (panels are L2-hot via 8-row XCD chunking).
// EPI: 0 = store bf16, 1 = exact GELU + store bf16
// ---------------------------------------------------------------------------
template<int EPI>
__launch_bounds__(256, 4)
__global__ void gemm_bt(const bf16* __restrict__ A, const bf16* __restrict__ Bt,
                        const float* __restrict__ bias, bf16* __restrict__ C,
                        int N, int K, int nbx, int nby) {
  __shared__ __align__(16) unsigned short smA[2][128*32];
  __shared__ __align__(16) unsigned short smB[2][128*32];

  const int nwg = nbx * nby;
  const int orig = blockIdx.x;
  const int q8 = nwg >> 3, r8 = nwg & 7;
  const int xcd = orig & 7, lin = orig >> 3;
  const int pid = (xcd < r8 ? xcd * (q8 + 1) : r8 * (q8 + 1) + (xcd - r8) * q8) + lin;
  const int pg = 8 * nbx;
  const int g = pid / pg;
  const int rem = pid - g * pg;
  const int rows = min(8, nby - g * 8);
  const int by = g * 8 + rem % rows;
  const int bx = rem / rows;

  const int t = threadIdx.x;
  const int l = t & 63, w = t >> 6;
  const int wr = w >> 1, wc = w & 1;
  const int brow = by * 128;
  const int bcol = bx * 128;

  f32x4 acc[4][4];
#pragma unroll
  for (int i = 0; i < 4; ++i)
#pragma unroll
    for (int j = 0; j < 4; ++j) acc[i][j] = (f32x4){0.f, 0.f, 0.f, 0.f};

  const int srow = t >> 2;
  const int scol = ((t & 3) ^ ((t >> 3) & 3)) * 8;
  const bf16* gA0 = A  + (size_t)(brow + srow) * K + scol;
  const bf16* gA1 = gA0 + (size_t)64 * K;
  const bf16* gB0 = Bt + (size_t)(bcol + srow) * K + scol;
  const bf16* gB1 = gB0 + (size_t)64 * K;

  const int arow = l & 15;
  const int aslot = (l >> 4) ^ ((arow >> 1) & 3);
  const int aoff = (wr*64 + arow)*32 + aslot*8;
  const int boff = (wc*64 + arow)*32 + aslot*8;

  auto stage = [&](int buf, int k0) {
    __builtin_amdgcn_global_load_lds((const __attribute__((address_space(1))) void*)(gA0 + k0),
                                     (__attribute__((address_space(3))) void*)(smA[buf] + w*512), 16, 0, 0);
    __builtin_amdgcn_global_load_lds((const __attribute__((address_space(1))) void*)(gA1 + k0),
                                     (__attribute__((address_space(3))) void*)(smA[buf] + 2048 + w*512), 16, 0, 0);
    __builtin_amdgcn_global_load_lds((const __attribute__((address_space(1))) void*)(gB0 + k0),
                                     (__attribute__((address_space(3))) void*)(smB[buf] + w*512), 16, 0, 0);
    __builtin_amdgcn_global_load_lds((const __attribute__((address_space(1))) void*)(gB1 + k0),
                                     (__attribute__((address_space(3))) void*)(smB[buf] + 2048 + w*512), 16, 0, 0);
  };

  const int nk = K >> 5;                 // >= 24 for all shapes
  stage(0, 0);
  stage(1, 32);

  for (int kt = 0; kt < nk; ++kt) {
    const int sl = kt & 1;
    // tile kt's 4 loads landed; tile kt+1's 4 may stay in flight
    if (kt + 1 < nk) asm volatile("s_waitcnt vmcnt(4)" ::: "memory");
    else             asm volatile("s_waitcnt vmcnt(0)" ::: "memory");
    __builtin_amdgcn_s_barrier();        // tile kt visible to all waves

    const unsigned short* sa = smA[sl] + aoff;
    const unsigned short* sb = smB[sl] + boff;
    bf16x8 af[4], bg[4];
#pragma unroll
    for (int i = 0; i < 4; ++i) {
      af[i] = *reinterpret_cast<const bf16x8*>(sa + i*512);
      bg[i] = *reinterpret_cast<const bf16x8*>(sb + i*512);
    }
    asm volatile("s_waitcnt lgkmcnt(0)" ::: "memory");   // own frag reads done
    __builtin_amdgcn_s_barrier();        // ALL waves' reads of slot sl done
    if (kt + 2 < nk) stage(sl, (kt + 2) << 5);   // overwrite just-read slot
    __builtin_amdgcn_sched_barrier(0);

    __builtin_amdgcn_s_setprio(1);
#pragma unroll
    for (int i = 0; i < 4; ++i)
#pragma unroll
      for (int j = 0; j < 4; ++j)
        acc[i][j] = __builtin_amdgcn_mfma_f32_16x16x32_bf16(af[i], bg[j], acc[i][j], 0, 0, 0);
    __builtin_amdgcn_s_setprio(0);
    __builtin_amdgcn_sched_barrier(0);
  }

#pragma unroll
  for (int i = 0; i < 4; ++i) {
    const int row = brow + wr*64 + i*16 + (l >> 4)*4;
#pragma unroll
    for (int j = 0; j < 4; ++j) {
      const int col = bcol + wc*64 + j*16 + (l & 15);
      const float bv = bias[col];
#pragma unroll
      for (int r = 0; r < 4; ++r) {
        float v = acc[i][j][r] + bv;
        if (EPI == 1) v = 0.5f * v * (1.0f + erff(v * 0.70710678118f));
        C[(size_t)(row + r) * N + col] = __float2bfloat16(v);
      }
    }
  }
}

// ---------------------------------------------------------------------------
// Classifier GEMM: 256x256 tile, 8 waves, BK=32, ring-4, 3-deep prefetch,
// 2 phases/tile. Epilogue: per-row-128 (max, sumexp) partials.
// ---------------------------------------------------------------------------
__launch_bounds__(512, 2)
__global__ void gemm_cls8(const bf16* __restrict__ A, const bf16* __restrict__ Bt,
                          const float* __restrict__ bias, float2* __restrict__ parts,
                          int K, int nbx, int nby) {
  __shared__ __align__(16) unsigned short lds[4][2][2][4096];  // ring, A/B, half

  const int nwg = nbx * nby;
  const int orig = blockIdx.x;
  const int q8 = nwg >> 3, r8 = nwg & 7;
  const int xcd = orig & 7, lin = orig >> 3;
  const int pid = (xcd < r8 ? xcd * (q8 + 1) : r8 * (q8 + 1) + (xcd - r8) * q8) + lin;
  const int pg = 8 * nbx;
  const int g = pid / pg;
  const int rem = pid - g * pg;
  const int rows = min(8, nby - g * 8);
  const int by = g * 8 + rem % rows;
  const int bx = rem / rows;

  const int t = threadIdx.x;            // 0..511
  const int l = t & 63, w = t >> 6;
  const int wm = w >> 2, wn = w & 3;    // 2 x 4 wave grid
  const int brow = by * 256;
  const int bcol = bx * 256;

  f32x4 acc[8][4];
#pragma unroll
  for (int m = 0; m < 8; ++m)
#pragma unroll
    for (int n = 0; n < 4; ++n) acc[m][n] = (f32x4){0.f, 0.f, 0.f, 0.f};

  const int srow = t >> 2;                        // 0..127
  const int scol = ((t & 3) ^ ((t >> 3) & 3)) * 8;
  const bf16* gA0 = A  + (size_t)(brow + srow) * K + scol;
  const bf16* gA1 = A  + (size_t)(brow + 128 + srow) * K + scol;
  const bf16* gB0 = Bt + (size_t)(bcol + srow) * K + scol;
  const bf16* gB1 = Bt + (size_t)(bcol + 128 + srow) * K + scol;

  const int arow = l & 15;
  const int aslot = (l >> 4) ^ ((arow >> 1) & 3);
  const int afrag = arow*32 + aslot*8;                       // + m*512
  const int bfrag = ((wn & 1)*64 + arow)*32 + aslot*8;       // + n*512

  auto stageA = [&](int rb, int k0) {
    __builtin_amdgcn_global_load_lds((const __attribute__((address_space(1))) void*)(gA0 + k0),
        (__attribute__((address_space(3))) void*)(&lds[rb][0][0][0] + w*512), 16, 0, 0);
    __builtin_amdgcn_global_load_lds((const __attribute__((address_space(1))) void*)(gA1 + k0),
        (__attribute__((address_space(3))) void*)(&lds[rb][0][1][0] + w*512), 16, 0, 0);
  };
  auto stageB = [&](int rb, int k0) {
    __builtin_amdgcn_global_load_lds((const __attribute__((address_space(1))) void*)(gB0 + k0),
        (__attribute__((address_space(3))) void*)(&lds[rb][1][0][0] + w*512), 16, 0, 0);
    __builtin_amdgcn_global_load_lds((const __attribute__((address_space(1))) void*)(gB1 + k0),
        (__attribute__((address_space(3))) void*)(&lds[rb][1][1][0] + w*512), 16, 0, 0);
  };

  const int nk = K >> 5;     // 24
  stageA(0, 0);   stageB(0, 0);
  stageA(1, 32);  stageB(1, 32);
  stageA(2, 64);  stageB(2, 64);

  for (int T = 0; T < nk; ++T) {
    const int rb = T & 3;
    if (T + 2 < nk)      asm volatile("s_waitcnt vmcnt(8)" ::: "memory");
    else if (T + 1 < nk) asm volatile("s_waitcnt vmcnt(4)" ::: "memory");
    else                 asm volatile("s_waitcnt vmcnt(0)" ::: "memory");
    __builtin_amdgcn_s_barrier();

    const unsigned short* sa = &lds[rb][0][wm][0] + afrag;
    const unsigned short* sb = &lds[rb][1][wn >> 1][0] + bfrag;

    bf16x8 af[8], bg[4];
#pragma unroll
    for (int m = 0; m < 4; ++m) af[m] = *reinterpret_cast<const bf16x8*>(sa + m*512);
#pragma unroll
    for (int n = 0; n < 4; ++n) bg[n] = *reinterpret_cast<const bf16x8*>(sb + n*512);
    if (T + 3 < nk) stageA((T + 3) & 3, (T + 3) << 5);
    asm volatile("s_waitcnt lgkmcnt(0)" ::: "memory");
    __builtin_amdgcn_sched_barrier(0);
    __builtin_amdgcn_s_setprio(1);
#pragma unroll
    for (int m = 0; m < 4; ++m)
#pragma unroll
      for (int n = 0; n < 4; ++n)
        acc[m][n] = __builtin_amdgcn_mfma_f32_16x16x32_bf16(af[m], bg[n], acc[m][n], 0, 0, 0);
    __builtin_amdgcn_s_setprio(0);
    __builtin_amdgcn_s_barrier();

#pragma unroll
    for (int m = 4; m < 8; ++m) af[m] = *reinterpret_cast<const bf16x8*>(sa + m*512);
    if (T + 3 < nk) stageB((T + 3) & 3, (T + 3) << 5);
    asm volatile("s_waitcnt lgkmcnt(0)" ::: "memory");
    __builtin_amdgcn_sched_barrier(0);
    __builtin_amdgcn_s_setprio(1);
#pragma unroll
    for (int m = 4; m < 8; ++m)
#pragma unroll
      for (int n = 0; n < 4; ++n)
        acc[m][n] = __builtin_amdgcn_mfma_f32_16x16x32_bf16(af[m], bg[n], acc[m][n], 0, 0, 0);
    __builtin_amdgcn_s_setprio(0);
  }

  __syncthreads();
  float* redm = reinterpret_cast<float*>(lds);       // [256][4]
  float* reds = redm + 1024;                         // [256][4]
  float b4[4];
#pragma unroll
  for (int n = 0; n < 4; ++n) b4[n] = bias[bcol + wn*64 + n*16 + (l & 15)];
  float vmax[8][4];
#pragma unroll
  for (int m = 0; m < 8; ++m)
#pragma unroll
    for (int r = 0; r < 4; ++r) {
      float mx = -3.0e38f;
#pragma unroll
      for (int n = 0; n < 4; ++n) mx = fmaxf(mx, acc[m][n][r] + b4[n]);
#pragma unroll
      for (int s = 1; s < 16; s <<= 1) mx = fmaxf(mx, __shfl_xor(mx, s));
      vmax[m][r] = mx;
    }
  if ((l & 15) == 0)
#pragma unroll
    for (int m = 0; m < 8; ++m)
#pragma unroll
      for (int r = 0; r < 4; ++r)
        redm[(wm*128 + m*16 + (l>>4)*4 + r)*4 + wn] = vmax[m][r];
  __syncthreads();
  const int pr = wn >> 1;
  float gmax[8][4], vsum[8][4];
#pragma unroll
  for (int m = 0; m < 8; ++m)
#pragma unroll
    for (int r = 0; r < 4; ++r) {
      const int rl = m*16 + (l>>4)*4 + r;
      const float gm = fmaxf(redm[(wm*128 + rl)*4 + pr*2], redm[(wm*128 + rl)*4 + pr*2 + 1]);
      gmax[m][r] = gm;
      float ss = 0.f;
#pragma unroll
      for (int n = 0; n < 4; ++n) ss += __expf(acc[m][n][r] + b4[n] - gm);
#pragma unroll
      for (int s = 1; s < 16; s <<= 1) ss += __shfl_xor(ss, s);
      vsum[m][r] = ss;
    }
  if ((l & 15) == 0)
#pragma unroll
    for (int m = 0; m < 8; ++m)
#pragma unroll
      for (int r = 0; r < 4; ++r)
        reds[(wm*128 + m*16 + (l>>4)*4 + r)*4 + wn] = vsum[m][r];
  __syncthreads();
  if ((wn & 1) == 0 && (l & 15) == 0)
#pragma unroll
    for (int m = 0; m < 8; ++m)
#pragma unroll
      for (int r = 0; r < 4; ++r) {
        const int rl = m*16 + (l>>4)*4 + r;
        const int row = brow + wm*128 + rl;
        parts[(size_t)row * NTCLS + bx*2 + pr] =
            make_float2(gmax[m][r], reds[(wm*128 + rl)*4 + wn] + reds[(wm*128 + rl)*4 + wn + 1]);
      }
}

// ---------------------------------------------------------------------------
// MFMA attention: one block (4 waves) per (batch, head). Wave w owns queries
// [w*32, w*32+32). LDS: Qs[128][64], Ks[128][64], Vt[64][128], P strips
// [32][128]/wave — all bf16, all XOR-swizzled (slot ^= row&7, 16B slots).
// ---------------------------------------------------------------------------
__launch_bounds__(256, 2)
__global__ void attn_mfma(const bf16* __restrict__ qkv, bf16* __restrict__ ctx) {
  const int bh = blockIdx.x;
  const int b = bh / NHEAD, h = bh % NHEAD;
  __shared__ __align__(16) unsigned char smem[81920];
  unsigned short* Qs = reinterpret_cast<unsigned short*>(smem);           // [128][64]
  unsigned short* Ks = reinterpret_cast<unsigned short*>(smem + 16384);   // [128][64]
  unsigned short* Vt = reinterpret_cast<unsigned short*>(smem + 32768);   // [64][128]

  const int t = threadIdx.x;
  const int l = t & 63, w = t >> 6;

  // ---- zero Vt (pad cols must be exact 0: 0*NaN hazard) + Q/K pad rows ----
  const float4 z4 = make_float4(0.f, 0.f, 0.f, 0.f);
#pragma unroll
  for (int rd = 0; rd < 4; ++rd)
    *reinterpret_cast<float4*>(smem + 32768 + (rd*256 + t)*16) = z4;
  if (t < 128) {
    const int mtx = t >> 6;            // 0 = Qs, 1 = Ks
    const int sl = t & 63;             // rows 120..127 x 8 slots
    *reinterpret_cast<float4*>(smem + mtx*16384 + (960 + sl)*16) = z4;
  }
  __syncthreads();

  // ---- stage Q,K via global_load_lds (pre-swizzled source); Vt transposed ----
  const bf16* qbase = qkv + (size_t)(b*SEQ)*2304 + h*DHEAD;
#pragma unroll
  for (int rd = 0; rd < 4; ++rd) {
    const int idx = rd*256 + t;
    if (idx < 960) {
      const int row = idx >> 3, slot = idx & 7;
      const int srccol = (slot ^ (row & 7)) * 8;
      const bf16* src = qbase + (size_t)row*2304 + srccol;
      __builtin_amdgcn_global_load_lds((const __attribute__((address_space(1))) void*)(src),
          (__attribute__((address_space(3))) void*)(Qs + idx*8), 16, 0, 0);
      __builtin_amdgcn_global_load_lds((const __attribute__((address_space(1))) void*)(src + HDIM),
          (__attribute__((address_space(3))) void*)(Ks + idx*8), 16, 0, 0);
    }
  }
#pragma unroll
  for (int rd = 0; rd < 4; ++rd) {
    const int e = rd*256 + t;
    if (e < 960) {
      const int j = e >> 3, d8 = (e & 7) * 8;
      bf16x8 vv = *reinterpret_cast<const bf16x8*>(qbase + (size_t)j*2304 + 2*HDIM + d8);
      const int cs = j >> 3;
#pragma unroll
      for (int q = 0; q < 8; ++q) {
        const int d = d8 + q;
        Vt[d*128 + ((cs ^ (d & 7))*8) + (j & 7)] =
            reinterpret_cast<const unsigned short*>(&vv)[q];
      }
    }
  }
  __syncthreads();   // drains vmcnt + lgkmcnt

  // ---- QK^T ----
  f32x4 sacc[2][8];
#pragma unroll
  for (int rt = 0; rt < 2; ++rt)
#pragma unroll
    for (int ct = 0; ct < 8; ++ct) sacc[rt][ct] = (f32x4){0.f, 0.f, 0.f, 0.f};

#pragma unroll
  for (int ks = 0; ks < 2; ++ks) {
    const int kslot = (l >> 4) + 4*ks;
    bf16x8 aq[2];
#pragma unroll
    for (int rt = 0; rt < 2; ++rt) {
      const int row = w*32 + rt*16 + (l & 15);
      aq[rt] = *reinterpret_cast<const bf16x8*>(Qs + row*64 + ((kslot ^ (row & 7))*8));
    }
#pragma unroll
    for (int ct = 0; ct < 8; ++ct) {
      const int rk = ct*16 + (l & 15);
      bf16x8 bk = *reinterpret_cast<const bf16x8*>(Ks + rk*64 + ((kslot ^ (rk & 7))*8));
#pragma unroll
      for (int rt = 0; rt < 2; ++rt)
        sacc[rt][ct] = __builtin_amdgcn_mfma_f32_16x16x32_bf16(aq[rt], bk, sacc[rt][ct], 0, 0, 0);
    }
  }

  // ---- mask + scale + softmax; write unnormalized P (bf16) to own strip ----
  unsigned short* Pw = reinterpret_cast<unsigned short*>(smem + 49152 + w*8192); // [32][128]
  float rinv[2][4];
#pragma unroll
  for (int rt = 0; rt < 2; ++rt) {
#pragma unroll
    for (int r = 0; r < 4; ++r) {
      const int i = w*32 + rt*16 + (l >> 4)*4 + r;
      float sv[8];
      float best = -3.0e38f;
#pragma unroll
      for (int ct = 0; ct < 8; ++ct) {
        const int j = ct*16 + (l & 15);
        const bool ok = (j < SEQ) && ((i < TITLEN) ? (j < TITLEN) : (j < TITLEN || j <= i));
        sv[ct] = ok ? sacc[rt][ct][r] * 0.125f : -1e30f;
        best = fmaxf(best, sv[ct]);
      }
#pragma unroll
      for (int m = 1; m < 16; m <<= 1) best = fmaxf(best, __shfl_xor(best, m));
      float ss = 0.f;
      const int rowl = rt*16 + (l >> 4)*4 + r;
#pragma unroll
      for (int ct = 0; ct < 8; ++ct) {
        const float p = __expf(sv[ct] - best);
        ss += p;
        const int col = ct*16 + (l & 15);
        const int cs = col >> 3;
        Pw[rowl*128 + ((cs ^ (rowl & 7))*8) + (col & 7)] = f2us(p);
      }
#pragma unroll
      for (int m = 1; m < 16; m <<= 1) ss += __shfl_xor(ss, m);
      rinv[rt][r] = 1.0f / ss;
    }
  }
  asm volatile("s_waitcnt lgkmcnt(0)" ::: "memory");   // own P writes complete
  __builtin_amdgcn_sched_barrier(0);                   // rule 18

  // ---- PV ----
  f32x4 oacc[2][4];
#pragma unroll
  for (int rt = 0; rt < 2; ++rt)
#pragma unroll
    for (int dt = 0; dt < 4; ++dt) oacc[rt][dt] = (f32x4){0.f, 0.f, 0.f, 0.f};

#pragma unroll
  for (int ks = 0; ks < 4; ++ks) {
    const int kslot = (l >> 4) + 4*ks;
    bf16x8 ap[2];
#pragma unroll
    for (int rt = 0; rt < 2; ++rt) {
      const int rowl = rt*16 + (l & 15);
      ap[rt] = *reinterpret_cast<const bf16x8*>(Pw + rowl*128 + ((kslot ^ (rowl & 7))*8));
    }
#pragma unroll
    for (int dt = 0; dt < 4; ++dt) {
      const int rv = dt*16 + (l & 15);
      bf16x8 bv = *reinterpret_cast<const bf16x8*>(Vt + rv*128 + ((kslot ^ (rv & 7))*8));
#pragma unroll
      for (int rt = 0; rt < 2; ++rt)
        oacc[rt][dt] = __builtin_amdgcn_mfma_f32_16x16x32_bf16(ap[rt], bv, oacc[rt][dt], 0, 0, 0);
    }
  }

  // ---- store ctx ----
  bf16* obase = ctx + (size_t)(b*SEQ)*HDIM + h*DHEAD;
#pragma unroll
  for (int rt = 0; rt < 2; ++rt)
#pragma unroll
    for (int r = 0; r < 4; ++r) {
      const int i = w*32 + rt*16 + (l >> 4)*4 + r;
      if (i < SEQ) {
#pragma unroll
        for (int dt = 0; dt < 4; ++dt) {
          const int d = dt*16 + (l & 15);
          obase[(size_t)i*HDIM + d] = __float2bfloat16(oacc[rt][dt][r] * rinv[rt][r]);
        }
      }
    }
}

// ---------------------------------------------------------------------------
// LN kernels (one wave per row), bf16 residual stream.
// ---------------------------------------------------------------------------
__launch_bounds__(64)
__global__ void embed_ln2(const int* __restrict__ x, const float* __restrict__ wemb,
                          const float* __restrict__ pemb, const float* __restrict__ temb,
                          const float* __restrict__ lw, const float* __restrict__ lb,
                          bf16* __restrict__ resid, bf16* __restrict__ hb) {
  const int row = blockIdx.x;
  const int s = row % SEQ;
  const int tok = x[row];
  const int l = threadIdx.x;
  const int c0 = l * 12;
  float v[12]; float sum = 0.f, sq = 0.f;
#pragma unroll
  for (int i = 0; i < 3; ++i) {
    const float4 a = *reinterpret_cast<const float4*>(wemb + (size_t)tok*HDIM + c0 + i*4);
    const float4 b = *reinterpret_cast<const float4*>(pemb + s*HDIM + c0 + i*4);
    const float4 c = *reinterpret_cast<const float4*>(temb + c0 + i*4);
    v[i*4+0] = a.x + b.x + c.x; v[i*4+1] = a.y + b.y + c.y;
    v[i*4+2] = a.z + b.z + c.z; v[i*4+3] = a.w + b.w + c.w;
#pragma unroll
    for (int e = 0; e < 4; ++e) { sum += v[i*4+e]; sq += v[i*4+e]*v[i*4+e]; }
  }
#pragma unroll
  for (int m = 1; m < 64; m <<= 1) { sum += __shfl_xor(sum, m); sq += __shfl_xor(sq, m); }
  const float mean = sum * (1.0f/HDIM);
  const float rs = rsqrtf(sq*(1.0f/HDIM) - mean*mean + 1e-12f);
  unsigned short* rp = (unsigned short*)resid + (size_t)row*HDIM + c0;
  unsigned short* hp = (unsigned short*)hb    + (size_t)row*HDIM + c0;
#pragma unroll
  for (int i = 0; i < 3; ++i) {
    ushort4 o;
    o.x = f2us((v[i*4+0]-mean)*rs*lw[c0+i*4+0] + lb[c0+i*4+0]);
    o.y = f2us((v[i*4+1]-mean)*rs*lw[c0+i*4+1] + lb[c0+i*4+1]);
    o.z = f2us((v[i*4+2]-mean)*rs*lw[c0+i*4+2] + lb[c0+i*4+2]);
    o.w = f2us((v[i*4+3]-mean)*rs*lw[c0+i*4+3] + lb[c0+i*4+3]);
    *reinterpret_cast<ushort4*>(hp + i*4) = o;
    ushort4 ro;
    ro.x = f2us(v[i*4+0]); ro.y = f2us(v[i*4+1]);
    ro.z = f2us(v[i*4+2]); ro.w = f2us(v[i*4+3]);
    *reinterpret_cast<ushort4*>(rp + i*4) = ro;
  }
}

__launch_bounds__(64)
__global__ void res_ln2(bf16* __restrict__ resid, bf16* __restrict__ hb,
                        const bf16* __restrict__ add,
                        const float* __restrict__ lw, const float* __restrict__ lb) {
  const int row = blockIdx.x;
  const int l = threadIdx.x;
  const int c0 = l * 12;
  const unsigned short* rp = (const unsigned short*)resid + (size_t)row*HDIM + c0;
  const unsigned short* ap = (const unsigned short*)add   + (size_t)row*HDIM + c0;
  float v[12]; float sum = 0.f, sq = 0.f;
#pragma unroll
  for (int i = 0; i < 3; ++i) {
    const ushort4 ra = *reinterpret_cast<const ushort4*>(rp + i*4);
    const ushort4 aa = *reinterpret_cast<const ushort4*>(ap + i*4);
    v[i*4+0] = us2f(ra.x) + us2f(aa.x);
    v[i*4+1] = us2f(ra.y) + us2f(aa.y);
    v[i*4+2] = us2f(ra.z) + us2f(aa.z);
    v[i*4+3] = us2f(ra.w) + us2f(aa.w);
#pragma unroll
    for (int e = 0; e < 4; ++e) { sum += v[i*4+e]; sq += v[i*4+e]*v[i*4+e]; }
  }
#pragma unroll
  for (int m = 1; m < 64; m <<= 1) { sum += __shfl_xor(sum, m); sq += __shfl_xor(sq, m); }
  const float mean = sum * (1.0f/HDIM);
  const float rs = rsqrtf(sq*(1.0f/HDIM) - mean*mean + 1e-12f);
  unsigned short* rw = (unsigned short*)resid + (size_t)row*HDIM + c0;
  unsigned short* hp = (unsigned short*)hb    + (size_t)row*HDIM + c0;
#pragma unroll
  for (int i = 0; i < 3; ++i) {
    ushort4 ro;
    ro.x = f2us(v[i*4+0]); ro.y = f2us(v[i*4+1]);
    ro.z = f2us(v[i*4+2]); ro.w = f2us(v[i*4+3]);
    *reinterpret_cast<ushort4*>(rw + i*4) = ro;
    ushort4 o;
    o.x = f2us((v[i*4+0]-mean)*rs*lw[c0+i*4+0] + lb[c0+i*4+0]);
    o.y = f2us((v[i*4+1]-mean)*rs*lw[c0+i*4+1] + lb[c0+i*4+1]);
    o.z = f2us((v[i*4+2]-mean)*rs*lw[c0+i*4+2] + lb[c0+i*4+2]);
    o.w = f2us((v[i*4+3]-mean)*rs*lw[c0+i*4+3] + lb[c0+i*4+3]);
    *reinterpret_cast<ushort4*>(hp + i*4) = o;
  }
}

// ---------------------------------------------------------------------------
// Weight transpose+convert (all 12 layers in one dispatch + per-layer fallback)
// ---------------------------------------------------------------------------
__device__ __forceinline__ void transpose_block(const float* in, bf16* out,
                                                int K, int N, int bx, int by) {
  __shared__ float tile[32][33];
  const int tx = threadIdx.x, ty = threadIdx.y;   // (32,8)
#pragma unroll
  for (int r = 0; r < 32; r += 8)
    tile[ty+r][tx] = in[(size_t)(by + ty + r) * N + bx + tx];
  __syncthreads();
#pragma unroll
  for (int r = 0; r < 32; r += 8)
    out[(size_t)(bx + ty + r) * K + by + tx] = __float2bfloat16(tile[tx][ty+r]);
}

__device__ __forceinline__ void transpose_sel(int id, int lay,
    const float* qw, const float* kw, const float* vw, const float* aow,
    const float* f1w, const float* f2w,
    bf16* wqkvT, bf16* waoT, bf16* wf1T, bf16* wf2T,
    size_t wstride_qkv, size_t wstride_ao, size_t wstride_f) {
  const size_t o768 = (size_t)768*768, of1 = (size_t)768*FFDIM;
  const float* in; bf16* out; int K, N, nbx;
  if (id < 2304) {
    const int z = id / 576; id -= z * 576;
    in = ((z == 0) ? qw : (z == 1) ? kw : (z == 2) ? vw : aow) + (size_t)lay*o768;
    out = (z < 3) ? (wqkvT + (size_t)lay*wstride_qkv + (size_t)z*o768)
                  : (waoT + (size_t)lay*wstride_ao);
    K = 768; N = 768; nbx = 24;
  } else if (id < 4608) {
    id -= 2304; in = f1w + (size_t)lay*of1; out = wf1T + (size_t)lay*wstride_f;
    K = 768; N = 3072; nbx = 96;
  } else {
    id -= 4608; in = f2w + (size_t)lay*of1; out = wf2T + (size_t)lay*wstride_f;
    K = 3072; N = 768; nbx = 24;
  }
  transpose_block(in, out, K, N, (id % nbx) * 32, (id / nbx) * 32);
}

__global__ void transpose_all(const float* qw, const float* kw, const float* vw,
                              const float* aow, const float* f1w, const float* f2w,
                              bf16* wqkvT, bf16* waoT, bf16* wf1T, bf16* wf2T) {
  transpose_sel(blockIdx.x % 6912, blockIdx.x / 6912, qw, kw, vw, aow, f1w, f2w,
                wqkvT, waoT, wf1T, wf2T,
                (size_t)2304*768, (size_t)768*768, (size_t)768*FFDIM);
}

__global__ void transpose_layer(const float* qw, const float* kw, const float* vw,
                                const float* aow, const float* f1w, const float* f2w,
                                bf16* wqkvT, bf16* waoT, bf16* wf1T, bf16* wf2T,
                                int lay) {
  transpose_sel(blockIdx.x, 0, qw + (size_t)lay*768*768, kw + (size_t)lay*768*768,
                vw + (size_t)lay*768*768, aow + (size_t)lay*768*768,
                f1w + (size_t)lay*768*FFDIM, f2w + (size_t)lay*768*FFDIM,
                wqkvT, waoT, wf1T, wf2T, 0, 0, 0);
}

__global__ void transpose_cls(const float* __restrict__ in, bf16* __restrict__ out) {
  __shared__ float tile[32][33];
  const int bx = blockIdx.x*32, by = blockIdx.y*32;
  const int tx = threadIdx.x, ty = threadIdx.y;   // (32,8)
#pragma unroll
  for (int r = 0; r < 32; r += 8) {
    const int n = bx + tx;
    tile[ty+r][tx] = (n < VOCAB) ? in[(size_t)(by + ty + r) * VOCAB + n] : 0.f;
  }
  __syncthreads();
#pragma unroll
  for (int r = 0; r < 32; r += 8) {
    const int n = bx + ty + r;
    if (n < VPAD) out[(size_t)n * 768 + by + tx] = __float2bfloat16(tile[tx][ty+r]);
  }
}

__global__ void prep_bias(const float* __restrict__ qb, const float* __restrict__ kb,
                          const float* __restrict__ vb, const float* __restrict__ clsb,
                          float* __restrict__ qkvb, float* __restrict__ clsbp) {
  const int i = blockIdx.x*256 + threadIdx.x;
  if (i < LNUM*2304) {
    const int l = i / 2304, n = i % 2304;
    float v;
    if (n < 768) v = qb[l*768 + n];
    else if (n < 1536) v = kb[l*768 + n - 768];
    else v = vb[l*768 + n - 1536];
    qkvb[i] = v;
  }
  if (i < VPAD) clsbp[i] = (i < VOCAB) ? clsb[i] : -1e9f;
}

__launch_bounds__(64)
__global__ void ce_merge(const float2* __restrict__ parts, const bf16* __restrict__ hb,
                         const bf16* __restrict__ wclsT, const float* __restrict__ clsb,
                         const int* __restrict__ y, float* __restrict__ out) {
  const int row = blockIdx.x;
  const int l = threadIdx.x;
  const int tgt = y[row];
  float tl = 0.f;
  for (int i = l; i < HDIM; i += 64)
    tl += __bfloat162float(hb[(size_t)row*HDIM + i]) * __bfloat162float(wclsT[(size_t)tgt*HDIM + i]);
#pragma unroll
  for (int m = 1; m < 64; m <<= 1) tl += __shfl_xor(tl, m);
  float mx = -3.0e38f;
  for (int i = l; i < NTCLS; i += 64) mx = fmaxf(mx, parts[(size_t)row*NTCLS + i].x);
#pragma unroll
  for (int m = 1; m < 64; m <<= 1) mx = fmaxf(mx, __shfl_xor(mx, m));
  float ss = 0.f;
  for (int i = l; i < NTCLS; i += 64) {
    const float2 p = parts[(size_t)row*NTCLS + i];
    ss += p.y * __expf(p.x - mx);
  }
#pragma unroll
  for (int m = 1; m < 64; m <<= 1) ss += __shfl_xor(ss, m);
  if (l == 0) {
    const float lse = mx + logf(ss);
    atomicAdd(out, (lse - (tl + clsb[tgt])) * (1.0f / MROWS));
  }
}

// ---------------------------------------------------------------------------
extern "C" void kernel_launch(void* const* d_in, const int* in_sizes, int n_in,
                              void* d_out, int out_size, void* d_ws, size_t ws_size,
                              hipStream_t stream) {
  const int*   x     = (const int*)d_in[0];
  const int*   y     = (const int*)d_in[1];
  const float* wemb  = (const float*)d_in[2];
  const float* pemb  = (const float*)d_in[3];
  const float* temb  = (const float*)d_in[4];
  const float* elnw  = (const float*)d_in[5];
  const float* elnb  = (const float*)d_in[6];
  const float* qw    = (const float*)d_in[7];
  const float* qb    = (const float*)d_in[8];
  const float* kw    = (const float*)d_in[9];
  const float* kb    = (const float*)d_in[10];
  const float* vw    = (const float*)d_in[11];
  const float* vb    = (const float*)d_in[12];
  const float* aow   = (const float*)d_in[13];
  const float* aob   = (const float*)d_in[14];
  const float* alnw  = (const float*)d_in[15];
  const float* alnb  = (const float*)d_in[16];
  const float* f1w   = (const float*)d_in[17];
  const float* f1b   = (const float*)d_in[18];
  const float* f2w   = (const float*)d_in[19];
  const float* f2b   = (const float*)d_in[20];
  const float* flnw  = (const float*)d_in[21];
  const float* flnb  = (const float*)d_in[22];
  const float* clsw  = (const float*)d_in[23];
  const float* clsb  = (const float*)d_in[24];

  char* p = (char*)d_ws;
  auto alloc = [&](size_t bytes) { char* r = p; p += (bytes + 255) & ~(size_t)255; return r; };
  bf16*  wclsT = (bf16*)alloc((size_t)VPAD*768*2);
  float* qkvb  = (float*)alloc((size_t)LNUM*2304*4);
  float* clsbp = (float*)alloc((size_t)VPAD*4);
  bf16*  resid = (bf16*)alloc((size_t)MROWS*HDIM*2);
  bf16*  hb    = (bf16*)alloc((size_t)MROWS*HDIM*2);
  bf16*  qkv   = (bf16*)alloc((size_t)MROWS*2304*2);
  bf16*  ctxb  = (bf16*)alloc((size_t)MROWS*HDIM*2);
  bf16*  tmp   = (bf16*)alloc((size_t)MROWS*HDIM*2);
  bf16*  ffh   = (bf16*)alloc((size_t)MROWS*FFDIM*2);
  float2* parts = (float2*)alloc((size_t)MROWS*NTCLS*sizeof(float2));

  const size_t sz_qkvT = (size_t)2304*768*2;
  const size_t sz_aoT  = (size_t)768*768*2;
  const size_t sz_fT   = (size_t)768*FFDIM*2;
  const size_t per_layer_w = ((sz_qkvT+255)&~255ULL) + ((sz_aoT+255)&~255ULL)
                           + 2*((sz_fT+255)&~255ULL);
  const size_t fixed = (size_t)(p - (char*)d_ws);
  const bool big = (fixed + (size_t)LNUM * per_layer_w) <= ws_size;
  const int nlw = big ? LNUM : 1;
  bf16* wqkvT = (bf16*)alloc((size_t)nlw * sz_qkvT);
  bf16* waoT  = (bf16*)alloc((size_t)nlw * sz_aoT);
  bf16* wf1T  = (bf16*)alloc((size_t)nlw * sz_fT);
  bf16* wf2T  = (bf16*)alloc((size_t)nlw * sz_fT);
  if ((size_t)(p - (char*)d_ws) > ws_size) {
    fprintf(stderr, "kernel_launch: ws too small (%zu > %zu)\n",
            (size_t)(p - (char*)d_ws), ws_size);
    return;
  }

  hipMemsetAsync(d_out, 0, (size_t)out_size * sizeof(float), stream);
  prep_bias<<<108, 256, 0, stream>>>(qb, kb, vb, clsb, qkvb, clsbp);
  transpose_cls<<<dim3(VPAD/32, 768/32), dim3(32,8), 0, stream>>>(clsw, wclsT);
  if (big)
    transpose_all<<<LNUM*6912, dim3(32,8), 0, stream>>>(qw, kw, vw, aow, f1w, f2w,
                                                        wqkvT, waoT, wf1T, wf2T);
  embed_ln2<<<MROWS, 64, 0, stream>>>(x, wemb, pemb, temb, elnw, elnb, resid, hb);

  for (int l = 0; l < LNUM; ++l) {
    bf16* lqkvT; bf16* laoT; bf16* lf1T; bf16* lf2T;
    if (big) {
      lqkvT = wqkvT + (size_t)l*2304*768;
      laoT  = waoT  + (size_t)l*768*768;
      lf1T  = wf1T  + (size_t)l*768*FFDIM;
      lf2T  = wf2T  + (size_t)l*768*FFDIM;
    } else {
      lqkvT = wqkvT; laoT = waoT; lf1T = wf1T; lf2T = wf2T;
      transpose_layer<<<6912, dim3(32,8), 0, stream>>>(qw, kw, vw, aow, f1w, f2w,
                                                       lqkvT, laoT, lf1T, lf2T, l);
    }

    gemm_bt<0><<<18*60, 256, 0, stream>>>(hb, lqkvT, qkvb + l*2304, qkv,
                                          2304, HDIM, 18, 60);
    attn_mfma<<<NBATCH*NHEAD, 256, 0, stream>>>(qkv, ctxb);
    gemm_bt<0><<<6*60, 256, 0, stream>>>(ctxb, laoT, aob + l*HDIM, tmp,
                                         768, HDIM, 6, 60);
    res_ln2<<<MROWS, 64, 0, stream>>>(resid, hb, tmp, alnw + l*HDIM, alnb + l*HDIM);
    gemm_bt<1><<<24*60, 256, 0, stream>>>(hb, lf1T, f1b + l*FFDIM, ffh,
                                          FFDIM, HDIM, 24, 60);
    gemm_bt<0><<<6*60, 256, 0, stream>>>(ffh, lf2T, f2b + l*HDIM, tmp,
                                         768, FFDIM, 6, 60);
    res_ln2<<<MROWS, 64, 0, stream>>>(resid, hb, tmp, flnw + l*HDIM, flnb + l*HDIM);
  }

  gemm_cls8<<<83*30, 512, 0, stream>>>(hb, wclsT, clsbp, parts, HDIM, 83, 30);
  ce_merge<<<MROWS, 64, 0, stream>>>(parts, hb, wclsT, clsb, y, (float*)d_out);
}